// Round 1
// 711.761 us; speedup vs baseline: 1.0078x; 1.0078x over previous
//
#include <hip/hip_runtime.h>
#include <math.h>

#define EPSV 1e-5f

// Shapes (fixed): B=64, C=2048, H=24, W=8 -> L=192, M=B*L=12288
// D_in2=384, Dssm=192, N=16, R=6

typedef __attribute__((ext_vector_type(8))) __bf16 bf16x8;
typedef __attribute__((ext_vector_type(4))) float f32x4;

__device__ __forceinline__ ushort f2bf(float f) {
  union { float f; unsigned u; } v; v.f = f;
  const unsigned r = v.u + 0x7fffu + ((v.u >> 16) & 1u);  // RNE
  return (ushort)(r >> 16);
}

// async 16B/lane global->LDS: LDS dest = wave-uniform base + lane*16
#define GLOAD16(G, L) __builtin_amdgcn_global_load_lds( \
    (__attribute__((address_space(1))) void*)(G), \
    (__attribute__((address_space(3))) void*)(L), 16, 0, 0)

// ---------------- fp32 -> bf16 convert ----------------
__global__ __launch_bounds__(256) void cvt_kernel(
    const float* __restrict__ s, ushort* __restrict__ d, int n)
{
  const int i = (blockIdx.x * 256 + threadIdx.x) * 4;
  if (i + 3 < n) {
    const float4 v = *(const float4*)(s + i);
    ushort4 o;
    o.x = f2bf(v.x); o.y = f2bf(v.y); o.z = f2bf(v.z); o.w = f2bf(v.w);
    *(ushort4*)(d + i) = o;
  }
}

// ---------------- transpose out_w (2048x192) -> bf16 out_wT (256x2048, pad 0) --
__global__ __launch_bounds__(256) void transpose_w(
    const float* __restrict__ w, ushort* __restrict__ wT)
{
  __shared__ float t[64][65];
  const int c0 = blockIdx.x * 64, d0 = blockIdx.y * 64;
  const int tl = threadIdx.x & 63, tg = threadIdx.x >> 6;
#pragma unroll
  for (int r = 0; r < 16; ++r) {
    const int c = r * 4 + tg;
    t[c][tl] = w[(size_t)(c0 + c) * 192 + d0 + tl];
  }
  __syncthreads();
#pragma unroll
  for (int r = 0; r < 16; ++r) {
    const int d = r * 4 + tg;
    wT[(size_t)(d0 + d) * 2048 + c0 + tl] = f2bf(t[tl][d]);
  }
}

// ---------------- LN stats: coalesced partial sums + atomics ----------------
__global__ __launch_bounds__(256) void ln_stats(
    const float* __restrict__ feat, float* __restrict__ sums)
{
  const int b = blockIdx.x, c0 = blockIdx.y * 128;
  const int l = threadIdx.x;
  if (l >= 192) return;
  const float* p = feat + ((size_t)b * 2048 + c0) * 192 + l;
  float s = 0.f, sq = 0.f;
  for (int c = 0; c < 128; ++c) { const float v = p[(size_t)c * 192]; s += v; sq = fmaf(v, v, sq); }
  atomicAdd(&sums[(b * 192 + l) * 2], s);
  atomicAdd(&sums[(b * 192 + l) * 2 + 1], sq);
}

// ---------------- LN apply + transpose -> bf16 fm (B*L, C) ----------------
__global__ __launch_bounds__(256) void ln_apply(
    const float* __restrict__ feat, const float* __restrict__ sums,
    const float* __restrict__ lnw, const float* __restrict__ lnb,
    ushort* __restrict__ fm)
{
  __shared__ float tile[64][65];
  __shared__ float smu[64], srs[64];
  const int b = blockIdx.x, c0 = blockIdx.y * 64, l0 = blockIdx.z * 64;
  const int tl = threadIdx.x & 63, tg = threadIdx.x >> 6;
#pragma unroll
  for (int r = 0; r < 16; ++r) {
    const int c = r * 4 + tg;
    tile[c][tl] = feat[((size_t)b * 2048 + c0 + c) * 192 + l0 + tl];
  }
  if (threadIdx.x < 64) {
    const float s  = sums[(b * 192 + l0 + threadIdx.x) * 2];
    const float sq = sums[(b * 192 + l0 + threadIdx.x) * 2 + 1];
    const float mu = s * (1.f / 2048.f);
    smu[threadIdx.x] = mu;
    srs[threadIdx.x] = rsqrtf(sq * (1.f / 2048.f) - mu * mu + EPSV);
  }
  __syncthreads();
  const float w = lnw[c0 + tl], bb = lnb[c0 + tl];
#pragma unroll
  for (int r = 0; r < 16; ++r) {
    const int ll = r * 4 + tg;
    fm[((size_t)(b * 192 + l0 + ll)) * 2048 + c0 + tl] =
        f2bf((tile[tl][ll] - smu[ll]) * srs[ll] * w + bb);
  }
}

// ---------------- MFMA K-phase: 128x128 tile, BK=32 (used by MODE 0/2) ------
__device__ __forceinline__ void mfma_phase(
    const ushort* __restrict__ Ag, int lda,
    const ushort* __restrict__ Bg, int ldb, int K,
    int bm, int bn, int tid, ushort* As, ushort* Bs, f32x4 acc[4][4])
{
  const int lane = tid & 63, wave = tid >> 6;
  const int wm = (wave & 1) << 6, wn = (wave >> 1) << 6;
  const int fr = lane & 15, q = lane >> 4;
  const int r0 = tid >> 2, kc = (tid & 3) << 3;   // staging row / k-chunk
  const int lb = (tid & 192) * 8;                 // wave-uniform LDS base (ushorts)
  for (int k0 = 0; k0 < K; k0 += 32) {
    __syncthreads();
    GLOAD16(Ag + (size_t)(bm + r0) * lda + k0 + kc,      As + lb);
    GLOAD16(Ag + (size_t)(bm + 64 + r0) * lda + k0 + kc, As + 2048 + lb);
    GLOAD16(Bg + (size_t)(bn + r0) * ldb + k0 + kc,      Bs + lb);
    GLOAD16(Bg + (size_t)(bn + 64 + r0) * ldb + k0 + kc, Bs + 2048 + lb);
    __syncthreads();
    bf16x8 af[4], bfr[4];
#pragma unroll
    for (int i = 0; i < 4; ++i) {
      af[i]  = *(const bf16x8*)&As[(wm + i * 16 + fr) * 32 + q * 8];
      bfr[i] = *(const bf16x8*)&Bs[(wn + i * 16 + fr) * 32 + q * 8];
    }
#pragma unroll
    for (int i = 0; i < 4; ++i)
#pragma unroll
      for (int j = 0; j < 4; ++j)
        acc[i][j] = __builtin_amdgcn_mfma_f32_16x16x32_bf16(af[i], bfr[j], acc[i][j], 0, 0, 0);
  }
}

// MODE 0: out = A1*B1^T + bias(p0), fp32 row-major ldc=384.
// MODE 2: outb = bf16(A1*B1^T), ldc=192, mask n<192 (W2 = mo_w @ out_w).
template<int MODE>
__global__ __launch_bounds__(256) void mfma_gemm(
    const ushort* __restrict__ A1, const ushort* __restrict__ B1,
    const float* __restrict__ p0,
    float* __restrict__ out, ushort* __restrict__ outb)
{
  __shared__ ushort As[4096], Bs[4096];
  const int tid = threadIdx.x;
  const int bm = blockIdx.y * 128, bn = blockIdx.x * 128;
  f32x4 acc[4][4];
#pragma unroll
  for (int i = 0; i < 4; ++i)
#pragma unroll
    for (int j = 0; j < 4; ++j) acc[i][j] = (f32x4)(0.f);

  mfma_phase(A1, 2048, B1, 2048, 2048, bm, bn, tid, As, Bs, acc);

  const int lane = tid & 63, wave = tid >> 6;
  const int wm = (wave & 1) << 6, wn = (wave >> 1) << 6;
  const int fr = lane & 15, q = lane >> 4;
  if (MODE == 0) {
#pragma unroll
    for (int mi = 0; mi < 4; ++mi) {
      const int m0 = bm + wm + mi * 16 + q * 4;
#pragma unroll
      for (int ni = 0; ni < 4; ++ni) {
        const int n = bn + wn + ni * 16 + fr;
        const float bias = p0[n];
#pragma unroll
        for (int r = 0; r < 4; ++r)
          out[(size_t)(m0 + r) * 384 + n] = acc[mi][ni][r] + bias;
      }
    }
  } else {
#pragma unroll
    for (int mi = 0; mi < 4; ++mi) {
      const int m0 = bm + wm + mi * 16 + q * 4;
#pragma unroll
      for (int ni = 0; ni < 4; ++ni) {
        const int n = bn + wn + ni * 16 + fr;
        if (n < 192) {
#pragma unroll
          for (int r = 0; r < 4; ++r)
            outb[(size_t)(m0 + r) * 192 + n] = f2bf(acc[mi][ni][r]);
        }
      }
    }
  }
}

// ============== Final GEMM: 192x256 tile, BK=64, 4-phase pipelined ==========
// C = fm@mo_w^T (K=2048) + ssm@W2^T (K=192), then relu(scale*x+shift),
// transposed store into out[(b*2048+n)*192 + l].
// 512 threads = 8 waves (2M x 4N), per-wave 96x64 output, acc[6][4].
// LDS: A [2][192][64] bf16 = 48KB, B [2][256][64] = 64KB -> 112KB, 1 block/CU.
// Swizzle: element (row,chunk8) stored at chunk slot chunk^(row&7) (involution,
// applied to the GLOBAL source on stage, and to the ds_read address on read ->
// linear global_load_lds dest stays legal; ds_read_b128 is bank-conflict-free).
// Pipeline: depth-2 prefetch, one counted s_waitcnt vmcnt(7) per K-tile,
// raw s_barrier (no vmcnt(0) drain in the main loop), setprio(1) around MFMA.

__device__ __forceinline__ void stage7(
    const ushort* __restrict__ Ag, int lda,
    const ushort* __restrict__ Bg, int ldb, int k0,
    int bm, int bn, int tid, ushort* Asl, ushort* Bsl)
{
  const int w = tid >> 6, l = tid & 63;
#pragma unroll
  for (int c = 0; c < 3; ++c) {                 // A: 3 x 8KB chunks (64 rows)
    const int LC = c * 512 + w * 64 + l;        // 16B slot index
    const int row = LC >> 3, sc = (LC & 7) ^ (row & 7);
    GLOAD16(Ag + (size_t)(bm + row) * lda + k0 + sc * 8, Asl + c * 4096 + w * 512);
  }
#pragma unroll
  for (int c = 0; c < 4; ++c) {                 // B: 4 x 8KB chunks
    const int LC = c * 512 + w * 64 + l;
    const int row = LC >> 3, sc = (LC & 7) ^ (row & 7);
    GLOAD16(Bg + (size_t)(bn + row) * ldb + k0 + sc * 8, Bsl + c * 4096 + w * 512);
  }
}

__global__ __launch_bounds__(512, 2) void mfma_gemm_big(
    const ushort* __restrict__ fmw,  const ushort* __restrict__ mow,
    const ushort* __restrict__ ssmb, const ushort* __restrict__ w2b,
    const float* __restrict__ scale, const float* __restrict__ shift,
    float* __restrict__ out)
{
  __shared__ ushort As[2 * 12288];   // [2][192][64]
  __shared__ ushort Bs[2 * 16384];   // [2][256][64]
  const int tid = threadIdx.x;
  const int flat = blockIdx.x;                 // 512 blocks
  const int bx = flat & 7, by = flat >> 3;     // XCD k <- bx=k: B-panel (1MB) L2-resident
  const int bm = by * 192, bn = bx * 256;

  const int lane = tid & 63, wave = tid >> 6;
  const int wr = wave >> 2, wc = wave & 3;     // 2M x 4N waves
  const int fr = lane & 15, q = lane >> 4;

  constexpr int NT = 35;                       // 32 tiles of K=2048 + 3 of K=192

  f32x4 acc[6][4];
#pragma unroll
  for (int i = 0; i < 6; ++i)
#pragma unroll
    for (int j = 0; j < 4; ++j) acc[i][j] = (f32x4)(0.f);

  // prologue: stage kt0 -> buf0, kt1 -> buf1; wait kt0 resident (7 newest in flight)
  stage7(fmw, 2048, mow, 2048, 0,  bm, bn, tid, As, Bs);
  stage7(fmw, 2048, mow, 2048, 64, bm, bn, tid, As + 12288, Bs + 16384);
  asm volatile("s_waitcnt vmcnt(7)" ::: "memory");
  asm volatile("" ::: "memory");
  __builtin_amdgcn_s_barrier();
  asm volatile("" ::: "memory");

  for (int kt = 0; kt < NT; ++kt) {
    const int cur = kt & 1;
    const ushort* Ab = As + cur * 12288;
    const ushort* Bb = Bs + cur * 16384;
    bf16x8 bfr[2][4];
#pragma unroll
    for (int ph = 0; ph < 4; ++ph) {
      const int mh = ph >> 1, ks = ph & 1;
      const int kswz = (((ks << 2) + q) ^ (fr & 7)) << 3;   // swizzled 8-elem chunk
      bf16x8 af[3];
#pragma unroll
      for (int mi = 0; mi < 3; ++mi)
        af[mi] = *(const bf16x8*)&Ab[(wr * 96 + (mh * 3 + mi) * 16 + fr) * 64 + kswz];
      if (ph < 2) {
#pragma unroll
        for (int ni = 0; ni < 4; ++ni)
          bfr[ks][ni] = *(const bf16x8*)&Bb[(wc * 64 + ni * 16 + fr) * 64 + kswz];
      }
      __builtin_amdgcn_s_barrier();
      __builtin_amdgcn_s_setprio(1);
#pragma unroll
      for (int mi = 0; mi < 3; ++mi)
#pragma unroll
        for (int ni = 0; ni < 4; ++ni)
          acc[mh * 3 + mi][ni] = __builtin_amdgcn_mfma_f32_16x16x32_bf16(
              af[mi], bfr[ks][ni], acc[mh * 3 + mi][ni], 0, 0, 0);
      __builtin_amdgcn_s_setprio(0);
      __builtin_amdgcn_s_barrier();            // all reads of this tile retired below here
    }
    // boundary: stage kt+2 into buf[cur] (fully consumed), counted wait on kt+1
    const int nk = kt + 2;
    if (nk < NT) {
      if (nk < 32)
        stage7(fmw, 2048, mow, 2048, nk * 64, bm, bn, tid,
               As + cur * 12288, Bs + cur * 16384);
      else
        stage7(ssmb, 192, w2b, 192, (nk - 32) * 64, bm, bn, tid,
               As + cur * 12288, Bs + cur * 16384);
      asm volatile("s_waitcnt vmcnt(7)" ::: "memory");   // kt+1 resident, kt+2 in flight
    } else if (kt + 1 < NT) {
      asm volatile("s_waitcnt vmcnt(0)" ::: "memory");   // tail only
    }
    asm volatile("" ::: "memory");
    __builtin_amdgcn_s_barrier();
    asm volatile("" ::: "memory");
  }

  // epilogue: relu(scale*x+shift), transposed float4 store
#pragma unroll
  for (int mi = 0; mi < 6; ++mi) {
    const int m0 = bm + wr * 96 + mi * 16 + q * 4;
    const int b = m0 / 192, l0 = m0 - b * 192;           // quad never straddles b
#pragma unroll
    for (int ni = 0; ni < 4; ++ni) {
      const int n = bn + wc * 64 + ni * 16 + fr;
      const float sc = scale[n], sh = shift[n];
      float4 o;
      o.x = fmaxf(fmaf(acc[mi][ni][0], sc, sh), 0.f);
      o.y = fmaxf(fmaf(acc[mi][ni][1], sc, sh), 0.f);
      o.z = fmaxf(fmaf(acc[mi][ni][2], sc, sh), 0.f);
      o.w = fmaxf(fmaf(acc[mi][ni][3], sc, sh), 0.f);
      *(float4*)(out + ((size_t)b * 2048 + n) * 192 + l0) = o;
    }
  }
}

// ---------------- x_proj + dt ----------------
__global__ __launch_bounds__(64) void xproj_kernel(
    const float* __restrict__ xz, const float* __restrict__ xpw,
    const float* __restrict__ dtw, float* __restrict__ dts,
    float* __restrict__ Bsb, float* __restrict__ Csb)
{
  const int m = blockIdx.x, tid = threadIdx.x;
  __shared__ float xrow[192];
  __shared__ float xdbl[38];
  const float* src = xz + (size_t)m * 384;
#pragma unroll
  for (int i = 0; i < 3; ++i) xrow[tid + i * 64] = src[tid + i * 64];
  __syncthreads();
  if (tid < 38) {
    float a = 0.f;
    const float* wr = xpw + tid * 192;
    for (int d = 0; d < 192; ++d) a = fmaf(xrow[d], wr[d], a);
    xdbl[tid] = a;
  }
  __syncthreads();
  if (tid < 16) Bsb[(size_t)m * 16 + tid] = xdbl[6 + tid];
  else if (tid < 32) Csb[(size_t)m * 16 + (tid - 16)] = xdbl[22 + (tid - 16)];
#pragma unroll
  for (int i = 0; i < 3; ++i) {
    const int d = tid + i * 64;
    const float* w = dtw + d * 6;
    float a = xdbl[0] * w[0] + xdbl[1] * w[1] + xdbl[2] * w[2]
            + xdbl[3] * w[3] + xdbl[4] * w[4] + xdbl[5] * w[5];
    dts[(size_t)m * 192 + d] = (a > 20.f) ? a : log1pf(__expf(a));
  }
}

// ---------------- bidirectional selective scan, LDS-staged -------------------
__global__ __launch_bounds__(256) void scan_kernel(
    const float* __restrict__ xz, const float* __restrict__ dts,
    const float* __restrict__ Bsb, const float* __restrict__ Csb,
    const float* __restrict__ A_logs, const float* __restrict__ Ds,
    ushort* __restrict__ ssm)
{
  __shared__ float s_dt[3072], s_x[3072], s_B[3072], s_C[3072], s_y[3072];
  const int tid = threadIdx.x;
  const int b = blockIdx.x / 12, dblk = blockIdx.x - b * 12;
  const int d0 = dblk * 16;
  const size_t rbase = (size_t)b * 192;
  for (int i = tid; i < 768; i += 256) {
    const int l = i >> 2, j = (i & 3) << 2;
    const size_t row = rbase + l;
    ((float4*)s_dt)[i] = *(const float4*)(dts + row * 192 + d0 + j);
    ((float4*)s_x)[i]  = *(const float4*)(xz  + row * 384 + d0 + j);
    ((float4*)s_B)[i]  = *(const float4*)(Bsb + row * 16 + j);
    ((float4*)s_C)[i]  = *(const float4*)(Csb + row * 16 + j);
  }
  __syncthreads();
  const int n = tid & 15, dl = tid >> 4;
  const float Acoef = -expf(A_logs[(d0 + dl) * 16 + n]);
  float u = 0.f;
#pragma unroll 4
  for (int l = 0; l < 192; ++l) {
    const float dt = s_dt[l * 16 + dl];
    const float c  = dt * s_B[l * 16 + n] * s_x[l * 16 + dl];
    const float a  = __expf(dt * Acoef);
    u = fmaf(a, u, c);
    float y = u * s_C[l * 16 + n];
    y += __shfl_xor(y, 1, 16); y += __shfl_xor(y, 2, 16);
    y += __shfl_xor(y, 4, 16); y += __shfl_xor(y, 8, 16);
    if (n == 0) s_y[l * 16 + dl] = y;
  }
  u = 0.f;
#pragma unroll 4
  for (int l = 191; l >= 0; --l) {
    const float dt = s_dt[l * 16 + dl];
    const float c  = dt * s_B[l * 16 + n] * s_x[l * 16 + dl];
    const float a  = __expf(dt * Acoef);
    u = fmaf(a, u, c);
    float y = u * s_C[l * 16 + n];
    y += __shfl_xor(y, 1, 16); y += __shfl_xor(y, 2, 16);
    y += __shfl_xor(y, 4, 16); y += __shfl_xor(y, 8, 16);
    if (n == 0) s_y[l * 16 + dl] += y;
  }
  __syncthreads();
  for (int i = tid; i < 768; i += 256) {
    const int l = i >> 2, j = (i & 3) << 2;
    const size_t row = rbase + l;
    const float4 y4 = ((const float4*)s_y)[i];
    const float4 x4 = ((const float4*)s_x)[i];
    const float4 z4 = *(const float4*)(xz + row * 384 + 192 + d0 + j);
    const float4 D4 = *(const float4*)(Ds + d0 + j);
    ushort4 o;
    o.x = f2bf((y4.x + 2.f * x4.x * D4.x) * (z4.x / (1.f + __expf(-z4.x))));
    o.y = f2bf((y4.y + 2.f * x4.y * D4.y) * (z4.y / (1.f + __expf(-z4.y))));
    o.z = f2bf((y4.z + 2.f * x4.z * D4.z) * (z4.z / (1.f + __expf(-z4.z))));
    o.w = f2bf((y4.w + 2.f * x4.w * D4.w) * (z4.w / (1.f + __expf(-z4.w))));
    *(ushort4*)(ssm + row * 192 + d0 + j) = o;
  }
}

// ---------------- BN prep ----------------
__global__ __launch_bounds__(64) void prep_kernel(
    const float* __restrict__ mo_w, const float* __restrict__ mo_b,
    const float* __restrict__ out_b,
    const float* __restrict__ bn_w, const float* __restrict__ bn_b,
    const float* __restrict__ bn_rm, const float* __restrict__ bn_rv,
    float* __restrict__ scale, float* __restrict__ shift)
{
  const int o = blockIdx.x, tid = threadIdx.x;
  float s = 0.f;
  for (int c = tid; c < 2048; c += 64) s = fmaf(mo_w[(size_t)o * 2048 + c], out_b[c], s);
#pragma unroll
  for (int off = 32; off > 0; off >>= 1) s += __shfl_down(s, off, 64);
  if (tid == 0) {
    const float b2 = s + mo_b[o];
    const float sc = bn_w[o] * rsqrtf(bn_rv[o] + EPSV);
    scale[o] = sc;
    shift[o] = (b2 - bn_rm[o]) * sc + bn_b[o];
  }
}

extern "C" void kernel_launch(void* const* d_in, const int* in_sizes, int n_in,
                              void* d_out, int out_size, void* d_ws, size_t ws_size,
                              hipStream_t stream) {
  const float* feat  = (const float*)d_in[0];
  const float* ln_w  = (const float*)d_in[1];
  const float* ln_b  = (const float*)d_in[2];
  const float* in_w  = (const float*)d_in[3];
  const float* in_b  = (const float*)d_in[4];
  const float* xpw   = (const float*)d_in[5];
  const float* dtw   = (const float*)d_in[6];
  const float* A_logs= (const float*)d_in[7];
  const float* Ds    = (const float*)d_in[8];
  const float* out_w = (const float*)d_in[9];
  const float* out_b = (const float*)d_in[10];
  const float* mo_w  = (const float*)d_in[11];
  const float* mo_b  = (const float*)d_in[12];
  const float* bn_w  = (const float*)d_in[13];
  const float* bn_b  = (const float*)d_in[14];
  const float* bn_rm = (const float*)d_in[15];
  const float* bn_rv = (const float*)d_in[16];
  float* out = (float*)d_out;

  // ---- workspace layout (bytes) ----
  uint8_t* p = (uint8_t*)d_ws;
  ushort* fm_b  = (ushort*)p; p += (size_t)12288 * 2048 * 2;  // 50331648
  float*  xz    = (float*)p;  p += (size_t)12288 * 384 * 4;   // 18874368
  float*  dts   = (float*)p;  p += (size_t)12288 * 192 * 4;   // 9437184
  float*  Bsb   = (float*)p;  p += (size_t)12288 * 16 * 4;    // 786432
  float*  Csb   = (float*)p;  p += (size_t)12288 * 16 * 4;    // 786432
  ushort* ssm_b = (ushort*)p; p += (size_t)12288 * 192 * 2;   // 4718592
  ushort* W2b   = (ushort*)p; p += (size_t)2048 * 192 * 2;    // 786432
  ushort* owT_b = (ushort*)p; p += (size_t)256 * 2048 * 2;    // 1048576 (padded)
  ushort* mo_wb = (ushort*)p; p += (size_t)2048 * 2048 * 2;   // 8388608
  ushort* in_wb = (ushort*)p; p += (size_t)384 * 2048 * 2;    // 1572864
  float*  scale = (float*)p;  p += 2048 * 4;
  float*  shift = (float*)p;  p += 2048 * 4;
  float*  sums  = (float*)p;  p += (size_t)64 * 192 * 2 * 4;  // 98304
  if ((size_t)(p - (uint8_t*)d_ws) > ws_size) return;

  // weights -> bf16 (+ padded transpose of out_w)
  cvt_kernel<<<4096, 256, 0, stream>>>(mo_w, mo_wb, 2048 * 2048);
  cvt_kernel<<<768, 256, 0, stream>>>(in_w, in_wb, 384 * 2048);
  hipMemsetAsync(owT_b, 0, (size_t)256 * 2048 * 2, stream);
  transpose_w<<<dim3(32, 3), 256, 0, stream>>>(out_w, owT_b);

  // LN (stats + apply/transpose -> bf16 fm)
  hipMemsetAsync(sums, 0, (size_t)64 * 192 * 2 * 4, stream);
  ln_stats<<<dim3(64, 16), 256, 0, stream>>>(feat, sums);
  ln_apply<<<dim3(64, 32, 3), 256, 0, stream>>>(feat, sums, ln_w, ln_b, fm_b);

  // GEMM1: xz = fm @ in_w^T + in_b   (M=12288, N=384, K=2048)
  mfma_gemm<0><<<dim3(3, 96), 256, 0, stream>>>(
      fm_b, in_wb, in_b, xz, nullptr);

  xproj_kernel<<<12288, 64, 0, stream>>>(xz, xpw, dtw, dts, Bsb, Csb);
  scan_kernel<<<768, 256, 0, stream>>>(xz, dts, Bsb, Csb, A_logs, Ds, ssm_b);

  // W2 = bf16(mo_w @ out_w)  (M=2048, N=192 padded to 256, K=2048)
  mfma_gemm<2><<<dim3(2, 16), 256, 0, stream>>>(
      mo_wb, owT_b, nullptr, nullptr, W2b);
  prep_kernel<<<2048, 64, 0, stream>>>(mo_w, mo_b, out_b, bn_w, bn_b, bn_rm, bn_rv, scale, shift);

  // Final: out = relu(bn(fm@mo_w^T + ssm@W2^T)), 192x256-tile 4-phase pipeline
  mfma_gemm_big<<<512, 512, 0, stream>>>(fm_b, mo_wb, ssm_b, W2b, scale, shift, out);
}

// Round 3
// 701.170 us; speedup vs baseline: 1.0230x; 1.0151x over previous
//
#include <hip/hip_runtime.h>
#include <math.h>

#define EPSV 1e-5f

// Shapes (fixed): B=64, C=2048, H=24, W=8 -> L=192, M=B*L=12288
// D_in2=384, Dssm=192, N=16, R=6

typedef __attribute__((ext_vector_type(8))) __bf16 bf16x8;
typedef __attribute__((ext_vector_type(4))) float f32x4;

__device__ __forceinline__ ushort f2bf(float f) {
  union { float f; unsigned u; } v; v.f = f;
  const unsigned r = v.u + 0x7fffu + ((v.u >> 16) & 1u);  // RNE
  return (ushort)(r >> 16);
}

// async 16B/lane global->LDS: LDS dest = wave-uniform base + lane*16
#define GLOAD16(G, L) __builtin_amdgcn_global_load_lds( \
    (__attribute__((address_space(1))) void*)(G), \
    (__attribute__((address_space(3))) void*)(L), 16, 0, 0)

#define BAR() do { asm volatile("" ::: "memory"); \
  __builtin_amdgcn_s_barrier(); \
  asm volatile("" ::: "memory"); } while (0)

// ---------------- fp32 -> bf16 convert ----------------
__global__ __launch_bounds__(256) void cvt_kernel(
    const float* __restrict__ s, ushort* __restrict__ d, int n)
{
  const int i = (blockIdx.x * 256 + threadIdx.x) * 4;
  if (i + 3 < n) {
    const float4 v = *(const float4*)(s + i);
    ushort4 o;
    o.x = f2bf(v.x); o.y = f2bf(v.y); o.z = f2bf(v.z); o.w = f2bf(v.w);
    *(ushort4*)(d + i) = o;
  }
}

// ---------------- transpose out_w (2048x192) -> bf16 out_wT (256x2048, pad 0) --
__global__ __launch_bounds__(256) void transpose_w(
    const float* __restrict__ w, ushort* __restrict__ wT)
{
  __shared__ float t[64][65];
  const int c0 = blockIdx.x * 64, d0 = blockIdx.y * 64;
  const int tl = threadIdx.x & 63, tg = threadIdx.x >> 6;
#pragma unroll
  for (int r = 0; r < 16; ++r) {
    const int c = r * 4 + tg;
    t[c][tl] = w[(size_t)(c0 + c) * 192 + d0 + tl];
  }
  __syncthreads();
#pragma unroll
  for (int r = 0; r < 16; ++r) {
    const int d = r * 4 + tg;
    wT[(size_t)(d0 + d) * 2048 + c0 + tl] = f2bf(t[tl][d]);
  }
}

// ---------------- LN stats: coalesced partial sums + atomics ----------------
__global__ __launch_bounds__(256) void ln_stats(
    const float* __restrict__ feat, float* __restrict__ sums)
{
  const int b = blockIdx.x, c0 = blockIdx.y * 128;
  const int l = threadIdx.x;
  if (l >= 192) return;
  const float* p = feat + ((size_t)b * 2048 + c0) * 192 + l;
  float s = 0.f, sq = 0.f;
  for (int c = 0; c < 128; ++c) { const float v = p[(size_t)c * 192]; s += v; sq = fmaf(v, v, sq); }
  atomicAdd(&sums[(b * 192 + l) * 2], s);
  atomicAdd(&sums[(b * 192 + l) * 2 + 1], sq);
}

// ---------------- LN apply + transpose -> bf16 fm (B*L, C) ----------------
__global__ __launch_bounds__(256) void ln_apply(
    const float* __restrict__ feat, const float* __restrict__ sums,
    const float* __restrict__ lnw, const float* __restrict__ lnb,
    ushort* __restrict__ fm)
{
  __shared__ float tile[64][65];
  __shared__ float smu[64], srs[64];
  const int b = blockIdx.x, c0 = blockIdx.y * 64, l0 = blockIdx.z * 64;
  const int tl = threadIdx.x & 63, tg = threadIdx.x >> 6;
#pragma unroll
  for (int r = 0; r < 16; ++r) {
    const int c = r * 4 + tg;
    tile[c][tl] = feat[((size_t)b * 2048 + c0 + c) * 192 + l0 + tl];
  }
  if (threadIdx.x < 64) {
    const float s  = sums[(b * 192 + l0 + threadIdx.x) * 2];
    const float sq = sums[(b * 192 + l0 + threadIdx.x) * 2 + 1];
    const float mu = s * (1.f / 2048.f);
    smu[threadIdx.x] = mu;
    srs[threadIdx.x] = rsqrtf(sq * (1.f / 2048.f) - mu * mu + EPSV);
  }
  __syncthreads();
  const float w = lnw[c0 + tl], bb = lnb[c0 + tl];
#pragma unroll
  for (int r = 0; r < 16; ++r) {
    const int ll = r * 4 + tg;
    fm[((size_t)(b * 192 + l0 + ll)) * 2048 + c0 + tl] =
        f2bf((tile[tl][ll] - smu[ll]) * srs[ll] * w + bb);
  }
}

// ---------------- MFMA K-phase: 128x128 tile, BK=32 (used by MODE 0/2) ------
__device__ __forceinline__ void mfma_phase(
    const ushort* __restrict__ Ag, int lda,
    const ushort* __restrict__ Bg, int ldb, int K,
    int bm, int bn, int tid, ushort* As, ushort* Bs, f32x4 acc[4][4])
{
  const int lane = tid & 63, wave = tid >> 6;
  const int wm = (wave & 1) << 6, wn = (wave >> 1) << 6;
  const int fr = lane & 15, q = lane >> 4;
  const int r0 = tid >> 2, kc = (tid & 3) << 3;   // staging row / k-chunk
  const int lb = (tid & 192) * 8;                 // wave-uniform LDS base (ushorts)
  for (int k0 = 0; k0 < K; k0 += 32) {
    __syncthreads();
    GLOAD16(Ag + (size_t)(bm + r0) * lda + k0 + kc,      As + lb);
    GLOAD16(Ag + (size_t)(bm + 64 + r0) * lda + k0 + kc, As + 2048 + lb);
    GLOAD16(Bg + (size_t)(bn + r0) * ldb + k0 + kc,      Bs + lb);
    GLOAD16(Bg + (size_t)(bn + 64 + r0) * ldb + k0 + kc, Bs + 2048 + lb);
    __syncthreads();
    bf16x8 af[4], bfr[4];
#pragma unroll
    for (int i = 0; i < 4; ++i) {
      af[i]  = *(const bf16x8*)&As[(wm + i * 16 + fr) * 32 + q * 8];
      bfr[i] = *(const bf16x8*)&Bs[(wn + i * 16 + fr) * 32 + q * 8];
    }
#pragma unroll
    for (int i = 0; i < 4; ++i)
#pragma unroll
      for (int j = 0; j < 4; ++j)
        acc[i][j] = __builtin_amdgcn_mfma_f32_16x16x32_bf16(af[i], bfr[j], acc[i][j], 0, 0, 0);
  }
}

// MODE 0: out = A1*B1^T + bias(p0), fp32 row-major ldc=384.
// MODE 2: outb = bf16(A1*B1^T), ldc=256 padded (W2 = mo_w @ out_w; cols>=192 are 0).
template<int MODE>
__global__ __launch_bounds__(256) void mfma_gemm(
    const ushort* __restrict__ A1, const ushort* __restrict__ B1,
    const float* __restrict__ p0,
    float* __restrict__ out, ushort* __restrict__ outb)
{
  __shared__ ushort As[4096], Bs[4096];
  const int tid = threadIdx.x;
  const int bm = blockIdx.y * 128, bn = blockIdx.x * 128;
  f32x4 acc[4][4];
#pragma unroll
  for (int i = 0; i < 4; ++i)
#pragma unroll
    for (int j = 0; j < 4; ++j) acc[i][j] = (f32x4)(0.f);

  mfma_phase(A1, 2048, B1, 2048, 2048, bm, bn, tid, As, Bs, acc);

  const int lane = tid & 63, wave = tid >> 6;
  const int wm = (wave & 1) << 6, wn = (wave >> 1) << 6;
  const int fr = lane & 15, q = lane >> 4;
  if (MODE == 0) {
#pragma unroll
    for (int mi = 0; mi < 4; ++mi) {
      const int m0 = bm + wm + mi * 16 + q * 4;
#pragma unroll
      for (int ni = 0; ni < 4; ++ni) {
        const int n = bn + wn + ni * 16 + fr;
        const float bias = p0[n];
#pragma unroll
        for (int r = 0; r < 4; ++r)
          out[(size_t)(m0 + r) * 384 + n] = acc[mi][ni][r] + bias;
      }
    }
  } else {
#pragma unroll
    for (int mi = 0; mi < 4; ++mi) {
      const int m0 = bm + wm + mi * 16 + q * 4;
#pragma unroll
      for (int ni = 0; ni < 4; ++ni) {
        const int n = bn + wn + ni * 16 + fr;
#pragma unroll
        for (int r = 0; r < 4; ++r)
          outb[(size_t)(m0 + r) * 256 + n] = f2bf(acc[mi][ni][r]);
      }
    }
  }
}

// ============== Final GEMM: 256x256 tile, BK=64, 8-phase m201 template ======
// C = fm@mo_w^T (K=2048, 32 tiles) + ssm@W2^T (K=256 zero-padded, 4 tiles),
// then relu(scale*x+shift), transposed store out[(b*2048+n)*192 + l].
// 512 threads = 8 waves (2M x 4N), wave tile 128x64, acc[8][4].
// LDS: A [2][256][64] + B [2][256][64] bf16 = 128 KiB -> 1 block/CU.
// Per phase: {ds_read 4-8 b128, stage half-tile(s), s_barrier, setprio(1),
// 16 MFMA, setprio(0), s_barrier}; counted vmcnt(4) once per K-tile.
// Stage map during tile t (slot-safe with 2 buffers):
//   ph0: A.lo(t+1), ph1: A.hi(t+1)  (target slot fully retired at end of t-1)
//   ph3: B.lo(t+2)+B.hi(t+2)        (B region of active slot fully read after ph2)
// Boundary invariant: only B(t+2) pair (4 loads) in flight -> vmcnt(4);
// every half needed for t+1 was issued >= 2.3 phases earlier.
// Swizzle: chunk slot c holds global chunk c^(row&7); pre-swizzled global src,
// linear LDS dest, XOR on ds_read address (involution both sides).

__device__ __forceinline__ void stage_half(
    int t, int kind,        // kind: 0=A.lo 1=A.hi 2=B.lo 3=B.hi
    int bm, int bn, int tid,
    const ushort* __restrict__ fmw, const ushort* __restrict__ mow,
    const ushort* __restrict__ ssmb, const ushort* __restrict__ w2b,
    ushort* As, ushort* Bs)
{
  const bool isA = (kind < 2);
  const ushort* G; int ld, k0;
  if (t < 32) { G = isA ? fmw : mow;  ld = 2048; k0 = t * 64; }
  else        { G = isA ? ssmb : w2b; ld = 256;  k0 = (t - 32) * 64; }
  const int p0 = isA ? bm : bn;
  ushort* L = (isA ? As : Bs) + (t & 1) * 16384 + (kind & 1) * 8192;
  const int w = tid >> 6, l = tid & 63;
#pragma unroll
  for (int j = 0; j < 2; ++j) {
    const int LC = j * 512 + w * 64 + l;              // 16B slot in half
    const int row = (kind & 1) * 128 + (LC >> 3);
    const int sc = (LC & 7) ^ (row & 7);
    GLOAD16(G + (size_t)(p0 + row) * ld + k0 + sc * 8, L + j * 4096 + w * 512);
  }
}

__global__ __launch_bounds__(512, 2) void mfma_gemm_big(
    const ushort* __restrict__ fmw,  const ushort* __restrict__ mow,
    const ushort* __restrict__ ssmb, const ushort* __restrict__ w2b,
    const float* __restrict__ scale, const float* __restrict__ shift,
    float* __restrict__ out)
{
  __shared__ ushort As[2 * 16384];   // [2][256][64]
  __shared__ ushort Bs[2 * 16384];
  const int tid = threadIdx.x;
  const int flat = blockIdx.x;                 // 384 blocks = 48 x 8
  const int bx = flat & 7, by = flat >> 3;     // bx = XCD id: B-panel L2-resident
  const int bm = by * 256, bn = bx * 256;

  const int lane = tid & 63, wave = tid >> 6;
  const int wr = wave >> 2, wc = wave & 3;     // 2M x 4N waves, tile 128x64
  const int fr = lane & 15, q = lane >> 4;

  constexpr int NT = 36;                       // 32 tiles K=2048 + 4 tiles K=256

  f32x4 acc[8][4];
#pragma unroll
  for (int i = 0; i < 8; ++i)
#pragma unroll
    for (int j = 0; j < 4; ++j) acc[i][j] = (f32x4)(0.f);

  // prologue: tile0 all 4 halves + B(1) pair; vmcnt(4) leaves B(1) in flight
  stage_half(0, 0, bm, bn, tid, fmw, mow, ssmb, w2b, As, Bs);
  stage_half(0, 1, bm, bn, tid, fmw, mow, ssmb, w2b, As, Bs);
  stage_half(0, 2, bm, bn, tid, fmw, mow, ssmb, w2b, As, Bs);
  stage_half(0, 3, bm, bn, tid, fmw, mow, ssmb, w2b, As, Bs);
  stage_half(1, 2, bm, bn, tid, fmw, mow, ssmb, w2b, As, Bs);
  stage_half(1, 3, bm, bn, tid, fmw, mow, ssmb, w2b, As, Bs);
  asm volatile("s_waitcnt vmcnt(4)" ::: "memory");
  BAR();

  for (int t = 0; t < NT; ++t) {
    const ushort* Ab = As + (t & 1) * 16384;
    const ushort* Bb = Bs + (t & 1) * 16384;
    bf16x8 bfr[4];
#pragma unroll
    for (int ph = 0; ph < 4; ++ph) {
      const int ks = ph >> 1, mh = ph & 1;
      const int kswz = (((ks << 2) + q) ^ (fr & 7)) << 3;
      bf16x8 af[4];
#pragma unroll
      for (int mi = 0; mi < 4; ++mi)
        af[mi] = *(const bf16x8*)&Ab[(wr * 128 + mh * 64 + mi * 16 + fr) * 64 + kswz];
      if (mh == 0) {
#pragma unroll
        for (int ni = 0; ni < 4; ++ni)
          bfr[ni] = *(const bf16x8*)&Bb[(wc * 64 + ni * 16 + fr) * 64 + kswz];
      }
      if (ph == 0) {
        if (t + 1 < NT) stage_half(t + 1, 0, bm, bn, tid, fmw, mow, ssmb, w2b, As, Bs);
      } else if (ph == 1) {
        if (t + 1 < NT) stage_half(t + 1, 1, bm, bn, tid, fmw, mow, ssmb, w2b, As, Bs);
      } else if (ph == 3) {
        if (t + 2 < NT) {
          stage_half(t + 2, 2, bm, bn, tid, fmw, mow, ssmb, w2b, As, Bs);
          stage_half(t + 2, 3, bm, bn, tid, fmw, mow, ssmb, w2b, As, Bs);
        }
      }
      BAR();
      __builtin_amdgcn_s_setprio(1);
#pragma unroll
      for (int mi = 0; mi < 4; ++mi)
#pragma unroll
        for (int ni = 0; ni < 4; ++ni)
          acc[mh * 4 + mi][ni] = __builtin_amdgcn_mfma_f32_16x16x32_bf16(
              af[mi], bfr[ni], acc[mh * 4 + mi][ni], 0, 0, 0);
      __builtin_amdgcn_s_setprio(0);
      if (ph == 3) {
        if (t <= 33) asm volatile("s_waitcnt vmcnt(4)" ::: "memory");
        else if (t == 34) asm volatile("s_waitcnt vmcnt(0)" ::: "memory");
      }
      BAR();
    }
  }

  // epilogue: relu(scale*x+shift), transposed float4 store
#pragma unroll
  for (int mi = 0; mi < 8; ++mi) {
    const int m0 = bm + wr * 128 + mi * 16 + q * 4;
    const int b = m0 / 192, l0 = m0 - b * 192;           // quad never straddles b
#pragma unroll
    for (int ni = 0; ni < 4; ++ni) {
      const int n = bn + wc * 64 + ni * 16 + fr;
      const float sc = scale[n], sh = shift[n];
      float4 o;
      o.x = fmaxf(fmaf(acc[mi][ni][0], sc, sh), 0.f);
      o.y = fmaxf(fmaf(acc[mi][ni][1], sc, sh), 0.f);
      o.z = fmaxf(fmaf(acc[mi][ni][2], sc, sh), 0.f);
      o.w = fmaxf(fmaf(acc[mi][ni][3], sc, sh), 0.f);
      *(float4*)(out + ((size_t)b * 2048 + n) * 192 + l0) = o;
    }
  }
}

// ---------------- x_proj + dt ----------------
__global__ __launch_bounds__(64) void xproj_kernel(
    const float* __restrict__ xz, const float* __restrict__ xpw,
    const float* __restrict__ dtw, float* __restrict__ dts,
    float* __restrict__ Bsb, float* __restrict__ Csb)
{
  const int m = blockIdx.x, tid = threadIdx.x;
  __shared__ float xrow[192];
  __shared__ float xdbl[38];
  const float* src = xz + (size_t)m * 384;
#pragma unroll
  for (int i = 0; i < 3; ++i) xrow[tid + i * 64] = src[tid + i * 64];
  __syncthreads();
  if (tid < 38) {
    float a = 0.f;
    const float* wr = xpw + tid * 192;
    for (int d = 0; d < 192; ++d) a = fmaf(xrow[d], wr[d], a);
    xdbl[tid] = a;
  }
  __syncthreads();
  if (tid < 16) Bsb[(size_t)m * 16 + tid] = xdbl[6 + tid];
  else if (tid < 32) Csb[(size_t)m * 16 + (tid - 16)] = xdbl[22 + (tid - 16)];
#pragma unroll
  for (int i = 0; i < 3; ++i) {
    const int d = tid + i * 64;
    const float* w = dtw + d * 6;
    float a = xdbl[0] * w[0] + xdbl[1] * w[1] + xdbl[2] * w[2]
            + xdbl[3] * w[3] + xdbl[4] * w[4] + xdbl[5] * w[5];
    dts[(size_t)m * 192 + d] = (a > 20.f) ? a : log1pf(__expf(a));
  }
}

// ---------------- bidirectional selective scan, LDS-staged -------------------
// ssm output stride is 256 (K-padded for the final GEMM; pad cols pre-zeroed).
__global__ __launch_bounds__(256) void scan_kernel(
    const float* __restrict__ xz, const float* __restrict__ dts,
    const float* __restrict__ Bsb, const float* __restrict__ Csb,
    const float* __restrict__ A_logs, const float* __restrict__ Ds,
    ushort* __restrict__ ssm)
{
  __shared__ float s_dt[3072], s_x[3072], s_B[3072], s_C[3072], s_y[3072];
  const int tid = threadIdx.x;
  const int b = blockIdx.x / 12, dblk = blockIdx.x - b * 12;
  const int d0 = dblk * 16;
  const size_t rbase = (size_t)b * 192;
  for (int i = tid; i < 768; i += 256) {
    const int l = i >> 2, j = (i & 3) << 2;
    const size_t row = rbase + l;
    ((float4*)s_dt)[i] = *(const float4*)(dts + row * 192 + d0 + j);
    ((float4*)s_x)[i]  = *(const float4*)(xz  + row * 384 + d0 + j);
    ((float4*)s_B)[i]  = *(const float4*)(Bsb + row * 16 + j);
    ((float4*)s_C)[i]  = *(const float4*)(Csb + row * 16 + j);
  }
  __syncthreads();
  const int n = tid & 15, dl = tid >> 4;
  const float Acoef = -expf(A_logs[(d0 + dl) * 16 + n]);
  float u = 0.f;
#pragma unroll 4
  for (int l = 0; l < 192; ++l) {
    const float dt = s_dt[l * 16 + dl];
    const float c  = dt * s_B[l * 16 + n] * s_x[l * 16 + dl];
    const float a  = __expf(dt * Acoef);
    u = fmaf(a, u, c);
    float y = u * s_C[l * 16 + n];
    y += __shfl_xor(y, 1, 16); y += __shfl_xor(y, 2, 16);
    y += __shfl_xor(y, 4, 16); y += __shfl_xor(y, 8, 16);
    if (n == 0) s_y[l * 16 + dl] = y;
  }
  u = 0.f;
#pragma unroll 4
  for (int l = 191; l >= 0; --l) {
    const float dt = s_dt[l * 16 + dl];
    const float c  = dt * s_B[l * 16 + n] * s_x[l * 16 + dl];
    const float a  = __expf(dt * Acoef);
    u = fmaf(a, u, c);
    float y = u * s_C[l * 16 + n];
    y += __shfl_xor(y, 1, 16); y += __shfl_xor(y, 2, 16);
    y += __shfl_xor(y, 4, 16); y += __shfl_xor(y, 8, 16);
    if (n == 0) s_y[l * 16 + dl] += y;
  }
  __syncthreads();
  for (int i = tid; i < 768; i += 256) {
    const int l = i >> 2, j = (i & 3) << 2;
    const size_t row = rbase + l;
    const float4 y4 = ((const float4*)s_y)[i];
    const float4 x4 = ((const float4*)s_x)[i];
    const float4 z4 = *(const float4*)(xz + row * 384 + 192 + d0 + j);
    const float4 D4 = *(const float4*)(Ds + d0 + j);
    ushort4 o;
    o.x = f2bf((y4.x + 2.f * x4.x * D4.x) * (z4.x / (1.f + __expf(-z4.x))));
    o.y = f2bf((y4.y + 2.f * x4.y * D4.y) * (z4.y / (1.f + __expf(-z4.y))));
    o.z = f2bf((y4.z + 2.f * x4.z * D4.z) * (z4.z / (1.f + __expf(-z4.z))));
    o.w = f2bf((y4.w + 2.f * x4.w * D4.w) * (z4.w / (1.f + __expf(-z4.w))));
    *(ushort4*)(ssm + row * 256 + d0 + j) = o;
  }
}

// ---------------- BN prep ----------------
__global__ __launch_bounds__(64) void prep_kernel(
    const float* __restrict__ mo_w, const float* __restrict__ mo_b,
    const float* __restrict__ out_b,
    const float* __restrict__ bn_w, const float* __restrict__ bn_b,
    const float* __restrict__ bn_rm, const float* __restrict__ bn_rv,
    float* __restrict__ scale, float* __restrict__ shift)
{
  const int o = blockIdx.x, tid = threadIdx.x;
  float s = 0.f;
  for (int c = tid; c < 2048; c += 64) s = fmaf(mo_w[(size_t)o * 2048 + c], out_b[c], s);
#pragma unroll
  for (int off = 32; off > 0; off >>= 1) s += __shfl_down(s, off, 64);
  if (tid == 0) {
    const float b2 = s + mo_b[o];
    const float sc = bn_w[o] * rsqrtf(bn_rv[o] + EPSV);
    scale[o] = sc;
    shift[o] = (b2 - bn_rm[o]) * sc + bn_b[o];
  }
}

extern "C" void kernel_launch(void* const* d_in, const int* in_sizes, int n_in,
                              void* d_out, int out_size, void* d_ws, size_t ws_size,
                              hipStream_t stream) {
  const float* feat  = (const float*)d_in[0];
  const float* ln_w  = (const float*)d_in[1];
  const float* ln_b  = (const float*)d_in[2];
  const float* in_w  = (const float*)d_in[3];
  const float* in_b  = (const float*)d_in[4];
  const float* xpw   = (const float*)d_in[5];
  const float* dtw   = (const float*)d_in[6];
  const float* A_logs= (const float*)d_in[7];
  const float* Ds    = (const float*)d_in[8];
  const float* out_w = (const float*)d_in[9];
  const float* out_b = (const float*)d_in[10];
  const float* mo_w  = (const float*)d_in[11];
  const float* mo_b  = (const float*)d_in[12];
  const float* bn_w  = (const float*)d_in[13];
  const float* bn_b  = (const float*)d_in[14];
  const float* bn_rm = (const float*)d_in[15];
  const float* bn_rv = (const float*)d_in[16];
  float* out = (float*)d_out;

  // ---- workspace layout (bytes) ----
  uint8_t* p = (uint8_t*)d_ws;
  ushort* fm_b  = (ushort*)p; p += (size_t)12288 * 2048 * 2;  // 50331648
  float*  xz    = (float*)p;  p += (size_t)12288 * 384 * 4;   // 18874368
  float*  dts   = (float*)p;  p += (size_t)12288 * 192 * 4;   // 9437184
  float*  Bsb   = (float*)p;  p += (size_t)12288 * 16 * 4;    // 786432
  float*  Csb   = (float*)p;  p += (size_t)12288 * 16 * 4;    // 786432
  ushort* ssm_b = (ushort*)p; p += (size_t)12288 * 256 * 2;   // 6291456 (K-pad 256)
  ushort* W2b   = (ushort*)p; p += (size_t)2048 * 256 * 2;    // 1048576 (K-pad 256)
  ushort* owT_b = (ushort*)p; p += (size_t)256 * 2048 * 2;    // 1048576 (padded)
  ushort* mo_wb = (ushort*)p; p += (size_t)2048 * 2048 * 2;   // 8388608
  ushort* in_wb = (ushort*)p; p += (size_t)384 * 2048 * 2;    // 1572864
  float*  scale = (float*)p;  p += 2048 * 4;
  float*  shift = (float*)p;  p += 2048 * 4;
  float*  sums  = (float*)p;  p += (size_t)64 * 192 * 2 * 4;  // 98304
  if ((size_t)(p - (uint8_t*)d_ws) > ws_size) return;

  // weights -> bf16 (+ padded transpose of out_w)
  cvt_kernel<<<4096, 256, 0, stream>>>(mo_w, mo_wb, 2048 * 2048);
  cvt_kernel<<<768, 256, 0, stream>>>(in_w, in_wb, 384 * 2048);
  hipMemsetAsync(owT_b, 0, (size_t)256 * 2048 * 2, stream);
  hipMemsetAsync(ssm_b, 0, (size_t)12288 * 256 * 2, stream);  // zero K-pad
  transpose_w<<<dim3(32, 3), 256, 0, stream>>>(out_w, owT_b);

  // LN (stats + apply/transpose -> bf16 fm)
  hipMemsetAsync(sums, 0, (size_t)64 * 192 * 2 * 4, stream);
  ln_stats<<<dim3(64, 16), 256, 0, stream>>>(feat, sums);
  ln_apply<<<dim3(64, 32, 3), 256, 0, stream>>>(feat, sums, ln_w, ln_b, fm_b);

  // GEMM1: xz = fm @ in_w^T + in_b   (M=12288, N=384, K=2048)
  mfma_gemm<0><<<dim3(3, 96), 256, 0, stream>>>(
      fm_b, in_wb, in_b, xz, nullptr);

  xproj_kernel<<<12288, 64, 0, stream>>>(xz, xpw, dtw, dts, Bsb, Csb);
  scan_kernel<<<768, 256, 0, stream>>>(xz, dts, Bsb, Csb, A_logs, Ds, ssm_b);

  // W2 = bf16(mo_w @ out_w)  (M=2048, N=192 padded to 256, K=2048), ldc=256
  mfma_gemm<2><<<dim3(2, 16), 256, 0, stream>>>(
      mo_wb, owT_b, nullptr, nullptr, W2b);
  prep_kernel<<<2048, 64, 0, stream>>>(mo_w, mo_b, out_b, bn_w, bn_b, bn_rm, bn_rv, scale, shift);

  // Final: out = relu(bn(fm@mo_w^T + ssm@W2^T)), 256x256 8-phase template
  mfma_gemm_big<<<384, 512, 0, stream>>>(fm_b, mo_wb, ssm_b, W2b, scale, shift, out);
}

// Round 4
// 608.679 us; speedup vs baseline: 1.1785x; 1.1520x over previous
//
#include <hip/hip_runtime.h>
#include <math.h>

#define EPSV 1e-5f

// Shapes (fixed): B=64, C=2048, H=24, W=8 -> L=192, M=B*L=12288
// D_in2=384, Dssm=192, N=16, R=6

typedef __attribute__((ext_vector_type(8))) __bf16 bf16x8;
typedef __attribute__((ext_vector_type(4))) float f32x4;

__device__ __forceinline__ ushort f2bf(float f) {
  union { float f; unsigned u; } v; v.f = f;
  const unsigned r = v.u + 0x7fffu + ((v.u >> 16) & 1u);  // RNE
  return (ushort)(r >> 16);
}

// async 16B/lane global->LDS: LDS dest = wave-uniform base + lane*16
#define GLOAD16(G, L) __builtin_amdgcn_global_load_lds( \
    (__attribute__((address_space(1))) void*)(G), \
    (__attribute__((address_space(3))) void*)(L), 16, 0, 0)

#define BAR() do { asm volatile("" ::: "memory"); \
  __builtin_amdgcn_s_barrier(); \
  asm volatile("" ::: "memory"); } while (0)

// DPP-based add of a permuted copy: y + perm(y). All within 16-lane DPP row.
template<int CTRL>
__device__ __forceinline__ float dpp_add(float y) {
  const int s = __builtin_amdgcn_update_dpp(0, __float_as_int(y), CTRL, 0xF, 0xF, true);
  return y + __int_as_float(s);
}
// full sum across the 16-lane row (n-group): quad xor1, xor2, then ror4, ror8
__device__ __forceinline__ float reduce16(float y) {
  y = dpp_add<0xB1>(y);    // quad_perm [1,0,3,2]
  y = dpp_add<0x4E>(y);    // quad_perm [2,3,0,1]
  y = dpp_add<0x124>(y);   // row_ror:4
  y = dpp_add<0x128>(y);   // row_ror:8
  return y;
}

// ---------------- fp32 -> bf16 convert ----------------
__global__ __launch_bounds__(256) void cvt_kernel(
    const float* __restrict__ s, ushort* __restrict__ d, int n)
{
  const int i = (blockIdx.x * 256 + threadIdx.x) * 4;
  if (i + 3 < n) {
    const float4 v = *(const float4*)(s + i);
    ushort4 o;
    o.x = f2bf(v.x); o.y = f2bf(v.y); o.z = f2bf(v.z); o.w = f2bf(v.w);
    *(ushort4*)(d + i) = o;
  }
}

// ---------------- transpose out_w (2048x192) -> bf16 out_wT (256x2048, pad 0) --
__global__ __launch_bounds__(256) void transpose_w(
    const float* __restrict__ w, ushort* __restrict__ wT)
{
  __shared__ float t[64][65];
  const int c0 = blockIdx.x * 64, d0 = blockIdx.y * 64;
  const int tl = threadIdx.x & 63, tg = threadIdx.x >> 6;
#pragma unroll
  for (int r = 0; r < 16; ++r) {
    const int c = r * 4 + tg;
    t[c][tl] = w[(size_t)(c0 + c) * 192 + d0 + tl];
  }
  __syncthreads();
#pragma unroll
  for (int r = 0; r < 16; ++r) {
    const int d = r * 4 + tg;
    wT[(size_t)(d0 + d) * 2048 + c0 + tl] = f2bf(t[tl][d]);
  }
}

// ---------------- LN stats: coalesced partial sums + atomics ----------------
__global__ __launch_bounds__(256) void ln_stats(
    const float* __restrict__ feat, float* __restrict__ sums)
{
  const int b = blockIdx.x, c0 = blockIdx.y * 128;
  const int l = threadIdx.x;
  if (l >= 192) return;
  const float* p = feat + ((size_t)b * 2048 + c0) * 192 + l;
  float s = 0.f, sq = 0.f;
  for (int c = 0; c < 128; ++c) { const float v = p[(size_t)c * 192]; s += v; sq = fmaf(v, v, sq); }
  atomicAdd(&sums[(b * 192 + l) * 2], s);
  atomicAdd(&sums[(b * 192 + l) * 2 + 1], sq);
}

// ---------------- LN apply + transpose -> bf16 fm (B*L, C) ----------------
__global__ __launch_bounds__(256) void ln_apply(
    const float* __restrict__ feat, const float* __restrict__ sums,
    const float* __restrict__ lnw, const float* __restrict__ lnb,
    ushort* __restrict__ fm)
{
  __shared__ float tile[64][65];
  __shared__ float smu[64], srs[64];
  const int b = blockIdx.x, c0 = blockIdx.y * 64, l0 = blockIdx.z * 64;
  const int tl = threadIdx.x & 63, tg = threadIdx.x >> 6;
#pragma unroll
  for (int r = 0; r < 16; ++r) {
    const int c = r * 4 + tg;
    tile[c][tl] = feat[((size_t)b * 2048 + c0 + c) * 192 + l0 + tl];
  }
  if (threadIdx.x < 64) {
    const float s  = sums[(b * 192 + l0 + threadIdx.x) * 2];
    const float sq = sums[(b * 192 + l0 + threadIdx.x) * 2 + 1];
    const float mu = s * (1.f / 2048.f);
    smu[threadIdx.x] = mu;
    srs[threadIdx.x] = rsqrtf(sq * (1.f / 2048.f) - mu * mu + EPSV);
  }
  __syncthreads();
  const float w = lnw[c0 + tl], bb = lnb[c0 + tl];
#pragma unroll
  for (int r = 0; r < 16; ++r) {
    const int ll = r * 4 + tg;
    fm[((size_t)(b * 192 + l0 + ll)) * 2048 + c0 + tl] =
        f2bf((tile[tl][ll] - smu[ll]) * srs[ll] * w + bb);
  }
}

// ---------------- MFMA K-phase: 128x128 tile, BK=32 (used by MODE 0/2) ------
__device__ __forceinline__ void mfma_phase(
    const ushort* __restrict__ Ag, int lda,
    const ushort* __restrict__ Bg, int ldb, int K,
    int bm, int bn, int tid, ushort* As, ushort* Bs, f32x4 acc[4][4])
{
  const int lane = tid & 63, wave = tid >> 6;
  const int wm = (wave & 1) << 6, wn = (wave >> 1) << 6;
  const int fr = lane & 15, q = lane >> 4;
  const int r0 = tid >> 2, kc = (tid & 3) << 3;   // staging row / k-chunk
  const int lb = (tid & 192) * 8;                 // wave-uniform LDS base (ushorts)
  for (int k0 = 0; k0 < K; k0 += 32) {
    __syncthreads();
    GLOAD16(Ag + (size_t)(bm + r0) * lda + k0 + kc,      As + lb);
    GLOAD16(Ag + (size_t)(bm + 64 + r0) * lda + k0 + kc, As + 2048 + lb);
    GLOAD16(Bg + (size_t)(bn + r0) * ldb + k0 + kc,      Bs + lb);
    GLOAD16(Bg + (size_t)(bn + 64 + r0) * ldb + k0 + kc, Bs + 2048 + lb);
    __syncthreads();
    bf16x8 af[4], bfr[4];
#pragma unroll
    for (int i = 0; i < 4; ++i) {
      af[i]  = *(const bf16x8*)&As[(wm + i * 16 + fr) * 32 + q * 8];
      bfr[i] = *(const bf16x8*)&Bs[(wn + i * 16 + fr) * 32 + q * 8];
    }
#pragma unroll
    for (int i = 0; i < 4; ++i)
#pragma unroll
      for (int j = 0; j < 4; ++j)
        acc[i][j] = __builtin_amdgcn_mfma_f32_16x16x32_bf16(af[i], bfr[j], acc[i][j], 0, 0, 0);
  }
}

// MODE 0: out = A1*B1^T + bias(p0), fp32 row-major ldc=384.
// MODE 2: outb = bf16(A1*B1^T), ldc=256 padded (W2 = mo_w @ out_w; cols>=192 are 0).
template<int MODE>
__global__ __launch_bounds__(256) void mfma_gemm(
    const ushort* __restrict__ A1, const ushort* __restrict__ B1,
    const float* __restrict__ p0,
    float* __restrict__ out, ushort* __restrict__ outb)
{
  __shared__ ushort As[4096], Bs[4096];
  const int tid = threadIdx.x;
  const int bm = blockIdx.y * 128, bn = blockIdx.x * 128;
  f32x4 acc[4][4];
#pragma unroll
  for (int i = 0; i < 4; ++i)
#pragma unroll
    for (int j = 0; j < 4; ++j) acc[i][j] = (f32x4)(0.f);

  mfma_phase(A1, 2048, B1, 2048, 2048, bm, bn, tid, As, Bs, acc);

  const int lane = tid & 63, wave = tid >> 6;
  const int wm = (wave & 1) << 6, wn = (wave >> 1) << 6;
  const int fr = lane & 15, q = lane >> 4;
  if (MODE == 0) {
#pragma unroll
    for (int mi = 0; mi < 4; ++mi) {
      const int m0 = bm + wm + mi * 16 + q * 4;
#pragma unroll
      for (int ni = 0; ni < 4; ++ni) {
        const int n = bn + wn + ni * 16 + fr;
        const float bias = p0[n];
#pragma unroll
        for (int r = 0; r < 4; ++r)
          out[(size_t)(m0 + r) * 384 + n] = acc[mi][ni][r] + bias;
      }
    }
  } else {
#pragma unroll
    for (int mi = 0; mi < 4; ++mi) {
      const int m0 = bm + wm + mi * 16 + q * 4;
#pragma unroll
      for (int ni = 0; ni < 4; ++ni) {
        const int n = bn + wn + ni * 16 + fr;
#pragma unroll
        for (int r = 0; r < 4; ++r)
          outb[(size_t)(m0 + r) * 256 + n] = f2bf(acc[mi][ni][r]);
      }
    }
  }
}

// ============== Final GEMM: 256x256 tile, BK=64, 8-phase m201 template ======
// (unchanged from round 3 — verified passing)
__device__ __forceinline__ void stage_half(
    int t, int kind,        // kind: 0=A.lo 1=A.hi 2=B.lo 3=B.hi
    int bm, int bn, int tid,
    const ushort* __restrict__ fmw, const ushort* __restrict__ mow,
    const ushort* __restrict__ ssmb, const ushort* __restrict__ w2b,
    ushort* As, ushort* Bs)
{
  const bool isA = (kind < 2);
  const ushort* G; int ld, k0;
  if (t < 32) { G = isA ? fmw : mow;  ld = 2048; k0 = t * 64; }
  else        { G = isA ? ssmb : w2b; ld = 256;  k0 = (t - 32) * 64; }
  const int p0 = isA ? bm : bn;
  ushort* L = (isA ? As : Bs) + (t & 1) * 16384 + (kind & 1) * 8192;
  const int w = tid >> 6, l = tid & 63;
#pragma unroll
  for (int j = 0; j < 2; ++j) {
    const int LC = j * 512 + w * 64 + l;              // 16B slot in half
    const int row = (kind & 1) * 128 + (LC >> 3);
    const int sc = (LC & 7) ^ (row & 7);
    GLOAD16(G + (size_t)(p0 + row) * ld + k0 + sc * 8, L + j * 4096 + w * 512);
  }
}

__global__ __launch_bounds__(512, 2) void mfma_gemm_big(
    const ushort* __restrict__ fmw,  const ushort* __restrict__ mow,
    const ushort* __restrict__ ssmb, const ushort* __restrict__ w2b,
    const float* __restrict__ scale, const float* __restrict__ shift,
    float* __restrict__ out)
{
  __shared__ ushort As[2 * 16384];   // [2][256][64]
  __shared__ ushort Bs[2 * 16384];
  const int tid = threadIdx.x;
  const int flat = blockIdx.x;                 // 384 blocks = 48 x 8
  const int bx = flat & 7, by = flat >> 3;     // bx = XCD id: B-panel L2-resident
  const int bm = by * 256, bn = bx * 256;

  const int lane = tid & 63, wave = tid >> 6;
  const int wr = wave >> 2, wc = wave & 3;     // 2M x 4N waves, tile 128x64
  const int fr = lane & 15, q = lane >> 4;

  constexpr int NT = 36;                       // 32 tiles K=2048 + 4 tiles K=256

  f32x4 acc[8][4];
#pragma unroll
  for (int i = 0; i < 8; ++i)
#pragma unroll
    for (int j = 0; j < 4; ++j) acc[i][j] = (f32x4)(0.f);

  // prologue: tile0 all 4 halves + B(1) pair; vmcnt(4) leaves B(1) in flight
  stage_half(0, 0, bm, bn, tid, fmw, mow, ssmb, w2b, As, Bs);
  stage_half(0, 1, bm, bn, tid, fmw, mow, ssmb, w2b, As, Bs);
  stage_half(0, 2, bm, bn, tid, fmw, mow, ssmb, w2b, As, Bs);
  stage_half(0, 3, bm, bn, tid, fmw, mow, ssmb, w2b, As, Bs);
  stage_half(1, 2, bm, bn, tid, fmw, mow, ssmb, w2b, As, Bs);
  stage_half(1, 3, bm, bn, tid, fmw, mow, ssmb, w2b, As, Bs);
  asm volatile("s_waitcnt vmcnt(4)" ::: "memory");
  BAR();

  for (int t = 0; t < NT; ++t) {
    const ushort* Ab = As + (t & 1) * 16384;
    const ushort* Bb = Bs + (t & 1) * 16384;
    bf16x8 bfr[4];
#pragma unroll
    for (int ph = 0; ph < 4; ++ph) {
      const int ks = ph >> 1, mh = ph & 1;
      const int kswz = (((ks << 2) + q) ^ (fr & 7)) << 3;
      bf16x8 af[4];
#pragma unroll
      for (int mi = 0; mi < 4; ++mi)
        af[mi] = *(const bf16x8*)&Ab[(wr * 128 + mh * 64 + mi * 16 + fr) * 64 + kswz];
      if (mh == 0) {
#pragma unroll
        for (int ni = 0; ni < 4; ++ni)
          bfr[ni] = *(const bf16x8*)&Bb[(wc * 64 + ni * 16 + fr) * 64 + kswz];
      }
      if (ph == 0) {
        if (t + 1 < NT) stage_half(t + 1, 0, bm, bn, tid, fmw, mow, ssmb, w2b, As, Bs);
      } else if (ph == 1) {
        if (t + 1 < NT) stage_half(t + 1, 1, bm, bn, tid, fmw, mow, ssmb, w2b, As, Bs);
      } else if (ph == 3) {
        if (t + 2 < NT) {
          stage_half(t + 2, 2, bm, bn, tid, fmw, mow, ssmb, w2b, As, Bs);
          stage_half(t + 2, 3, bm, bn, tid, fmw, mow, ssmb, w2b, As, Bs);
        }
      }
      BAR();
      __builtin_amdgcn_s_setprio(1);
#pragma unroll
      for (int mi = 0; mi < 4; ++mi)
#pragma unroll
        for (int ni = 0; ni < 4; ++ni)
          acc[mh * 4 + mi][ni] = __builtin_amdgcn_mfma_f32_16x16x32_bf16(
              af[mi], bfr[ni], acc[mh * 4 + mi][ni], 0, 0, 0);
      __builtin_amdgcn_s_setprio(0);
      if (ph == 3) {
        if (t <= 33) asm volatile("s_waitcnt vmcnt(4)" ::: "memory");
        else if (t == 34) asm volatile("s_waitcnt vmcnt(0)" ::: "memory");
      }
      BAR();
    }
  }

  // epilogue: relu(scale*x+shift), transposed float4 store
#pragma unroll
  for (int mi = 0; mi < 8; ++mi) {
    const int m0 = bm + wr * 128 + mi * 16 + q * 4;
    const int b = m0 / 192, l0 = m0 - b * 192;           // quad never straddles b
#pragma unroll
    for (int ni = 0; ni < 4; ++ni) {
      const int n = bn + wc * 64 + ni * 16 + fr;
      const float sc = scale[n], sh = shift[n];
      float4 o;
      o.x = fmaxf(fmaf(acc[mi][ni][0], sc, sh), 0.f);
      o.y = fmaxf(fmaf(acc[mi][ni][1], sc, sh), 0.f);
      o.z = fmaxf(fmaf(acc[mi][ni][2], sc, sh), 0.f);
      o.w = fmaxf(fmaf(acc[mi][ni][3], sc, sh), 0.f);
      *(float4*)(out + ((size_t)b * 2048 + n) * 192 + l0) = o;
    }
  }
}

// ---------------- x_proj + dt ----------------
__global__ __launch_bounds__(64) void xproj_kernel(
    const float* __restrict__ xz, const float* __restrict__ xpw,
    const float* __restrict__ dtw, float* __restrict__ dts,
    float* __restrict__ Bsb, float* __restrict__ Csb)
{
  const int m = blockIdx.x, tid = threadIdx.x;
  __shared__ float xrow[192];
  __shared__ float xdbl[38];
  const float* src = xz + (size_t)m * 384;
#pragma unroll
  for (int i = 0; i < 3; ++i) xrow[tid + i * 64] = src[tid + i * 64];
  __syncthreads();
  if (tid < 38) {
    float a = 0.f;
    const float* wr = xpw + tid * 192;
    for (int d = 0; d < 192; ++d) a = fmaf(xrow[d], wr[d], a);
    xdbl[tid] = a;
  }
  __syncthreads();
  if (tid < 16) Bsb[(size_t)m * 16 + tid] = xdbl[6 + tid];
  else if (tid < 32) Csb[(size_t)m * 16 + (tid - 16)] = xdbl[22 + (tid - 16)];
#pragma unroll
  for (int i = 0; i < 3; ++i) {
    const int d = tid + i * 64;
    const float* w = dtw + d * 6;
    float a = xdbl[0] * w[0] + xdbl[1] * w[1] + xdbl[2] * w[2]
            + xdbl[3] * w[3] + xdbl[4] * w[4] + xdbl[5] * w[5];
    dts[(size_t)m * 192 + d] = (a > 20.f) ? a : log1pf(__expf(a));
  }
}

// ---------------- bidirectional selective scan, transposed-LDS + DPP reduce --
// grid = B * (192/16) = 768 blocks; 256 threads: (dl = tid>>4, n = tid&15).
// LDS layout [16][196] (pad 196 -> 4n mod 32 banks, 2-way max = free).
// Per 4 l-steps: 1 ds_read_b128 per array; n-reduction via 4 DPP VALU adds
// (quad_perm xor1/xor2 + row_ror 4/8 over the 16-lane row) — no LDS shuffles.
// ssm output stride 256 (K-padded for the final GEMM; pad cols pre-zeroed).
__global__ __launch_bounds__(256) void scan_kernel(
    const float* __restrict__ xz, const float* __restrict__ dts,
    const float* __restrict__ Bsb, const float* __restrict__ Csb,
    const float* __restrict__ A_logs, const float* __restrict__ Ds,
    ushort* __restrict__ ssm)
{
  __shared__ float s_dt[16 * 196], s_x[16 * 196], s_B[16 * 196],
                   s_C[16 * 196], s_y[16 * 196];
  const int tid = threadIdx.x;
  const int b = blockIdx.x / 12, dblk = blockIdx.x - b * 12;
  const int d0 = dblk * 16;
  const size_t rbase = (size_t)b * 192;
  // staging: float4 global reads, transposed scalar LDS writes
  for (int i = tid; i < 768; i += 256) {
    const int l = i >> 2, j = (i & 3) << 2;
    const size_t row = rbase + l;
    const float4 dtv = *(const float4*)(dts + row * 192 + d0 + j);
    const float4 xv  = *(const float4*)(xz  + row * 384 + d0 + j);
    const float4 Bv  = *(const float4*)(Bsb + row * 16 + j);
    const float4 Cv  = *(const float4*)(Csb + row * 16 + j);
    s_dt[(j + 0) * 196 + l] = dtv.x; s_dt[(j + 1) * 196 + l] = dtv.y;
    s_dt[(j + 2) * 196 + l] = dtv.z; s_dt[(j + 3) * 196 + l] = dtv.w;
    s_x [(j + 0) * 196 + l] = xv.x;  s_x [(j + 1) * 196 + l] = xv.y;
    s_x [(j + 2) * 196 + l] = xv.z;  s_x [(j + 3) * 196 + l] = xv.w;
    s_B [(j + 0) * 196 + l] = Bv.x;  s_B [(j + 1) * 196 + l] = Bv.y;
    s_B [(j + 2) * 196 + l] = Bv.z;  s_B [(j + 3) * 196 + l] = Bv.w;
    s_C [(j + 0) * 196 + l] = Cv.x;  s_C [(j + 1) * 196 + l] = Cv.y;
    s_C [(j + 2) * 196 + l] = Cv.z;  s_C [(j + 3) * 196 + l] = Cv.w;
  }
  __syncthreads();
  const int n = tid & 15, dl = tid >> 4;
  const float Acoef = -expf(A_logs[(d0 + dl) * 16 + n]);
  const float* pdt = s_dt + dl * 196;
  const float* px  = s_x  + dl * 196;
  const float* pB  = s_B  + n * 196;
  const float* pC  = s_C  + n * 196;
  float* py = s_y + dl * 196;
  float u = 0.f;
  for (int l0 = 0; l0 < 192; l0 += 4) {
    const float4 dtv = *(const float4*)(pdt + l0);
    const float4 xv  = *(const float4*)(px + l0);
    const float4 Bv  = *(const float4*)(pB + l0);
    const float4 Cv  = *(const float4*)(pC + l0);
    u = fmaf(__expf(dtv.x * Acoef), u, dtv.x * Bv.x * xv.x);
    { float y = reduce16(u * Cv.x); if (n == 0) py[l0 + 0] = y; }
    u = fmaf(__expf(dtv.y * Acoef), u, dtv.y * Bv.y * xv.y);
    { float y = reduce16(u * Cv.y); if (n == 0) py[l0 + 1] = y; }
    u = fmaf(__expf(dtv.z * Acoef), u, dtv.z * Bv.z * xv.z);
    { float y = reduce16(u * Cv.z); if (n == 0) py[l0 + 2] = y; }
    u = fmaf(__expf(dtv.w * Acoef), u, dtv.w * Bv.w * xv.w);
    { float y = reduce16(u * Cv.w); if (n == 0) py[l0 + 3] = y; }
  }
  u = 0.f;
  for (int l0 = 188; l0 >= 0; l0 -= 4) {
    const float4 dtv = *(const float4*)(pdt + l0);
    const float4 xv  = *(const float4*)(px + l0);
    const float4 Bv  = *(const float4*)(pB + l0);
    const float4 Cv  = *(const float4*)(pC + l0);
    u = fmaf(__expf(dtv.w * Acoef), u, dtv.w * Bv.w * xv.w);
    { float y = reduce16(u * Cv.w); if (n == 0) py[l0 + 3] += y; }
    u = fmaf(__expf(dtv.z * Acoef), u, dtv.z * Bv.z * xv.z);
    { float y = reduce16(u * Cv.z); if (n == 0) py[l0 + 2] += y; }
    u = fmaf(__expf(dtv.y * Acoef), u, dtv.y * Bv.y * xv.y);
    { float y = reduce16(u * Cv.y); if (n == 0) py[l0 + 1] += y; }
    u = fmaf(__expf(dtv.x * Acoef), u, dtv.x * Bv.x * xv.x);
    { float y = reduce16(u * Cv.x); if (n == 0) py[l0 + 0] += y; }
  }
  __syncthreads();
  // epilogue: (yf+yb + 2*x*D) * silu(z) -> bf16
  for (int i = tid; i < 768; i += 256) {
    const int l = i >> 2, j = (i & 3) << 2;
    const size_t row = rbase + l;
    float4 y4, x4;
    y4.x = s_y[(j + 0) * 196 + l]; y4.y = s_y[(j + 1) * 196 + l];
    y4.z = s_y[(j + 2) * 196 + l]; y4.w = s_y[(j + 3) * 196 + l];
    x4.x = s_x[(j + 0) * 196 + l]; x4.y = s_x[(j + 1) * 196 + l];
    x4.z = s_x[(j + 2) * 196 + l]; x4.w = s_x[(j + 3) * 196 + l];
    const float4 z4 = *(const float4*)(xz + row * 384 + 192 + d0 + j);
    const float4 D4 = *(const float4*)(Ds + d0 + j);
    ushort4 o;
    o.x = f2bf((y4.x + 2.f * x4.x * D4.x) * (z4.x / (1.f + __expf(-z4.x))));
    o.y = f2bf((y4.y + 2.f * x4.y * D4.y) * (z4.y / (1.f + __expf(-z4.y))));
    o.z = f2bf((y4.z + 2.f * x4.z * D4.z) * (z4.z / (1.f + __expf(-z4.z))));
    o.w = f2bf((y4.w + 2.f * x4.w * D4.w) * (z4.w / (1.f + __expf(-z4.w))));
    *(ushort4*)(ssm + row * 256 + d0 + j) = o;
  }
}

// ---------------- BN prep ----------------
__global__ __launch_bounds__(64) void prep_kernel(
    const float* __restrict__ mo_w, const float* __restrict__ mo_b,
    const float* __restrict__ out_b,
    const float* __restrict__ bn_w, const float* __restrict__ bn_b,
    const float* __restrict__ bn_rm, const float* __restrict__ bn_rv,
    float* __restrict__ scale, float* __restrict__ shift)
{
  const int o = blockIdx.x, tid = threadIdx.x;
  float s = 0.f;
  for (int c = tid; c < 2048; c += 64) s = fmaf(mo_w[(size_t)o * 2048 + c], out_b[c], s);
#pragma unroll
  for (int off = 32; off > 0; off >>= 1) s += __shfl_down(s, off, 64);
  if (tid == 0) {
    const float b2 = s + mo_b[o];
    const float sc = bn_w[o] * rsqrtf(bn_rv[o] + EPSV);
    scale[o] = sc;
    shift[o] = (b2 - bn_rm[o]) * sc + bn_b[o];
  }
}

extern "C" void kernel_launch(void* const* d_in, const int* in_sizes, int n_in,
                              void* d_out, int out_size, void* d_ws, size_t ws_size,
                              hipStream_t stream) {
  const float* feat  = (const float*)d_in[0];
  const float* ln_w  = (const float*)d_in[1];
  const float* ln_b  = (const float*)d_in[2];
  const float* in_w  = (const float*)d_in[3];
  const float* in_b  = (const float*)d_in[4];
  const float* xpw   = (const float*)d_in[5];
  const float* dtw   = (const float*)d_in[6];
  const float* A_logs= (const float*)d_in[7];
  const float* Ds    = (const float*)d_in[8];
  const float* out_w = (const float*)d_in[9];
  const float* out_b = (const float*)d_in[10];
  const float* mo_w  = (const float*)d_in[11];
  const float* mo_b  = (const float*)d_in[12];
  const float* bn_w  = (const float*)d_in[13];
  const float* bn_b  = (const float*)d_in[14];
  const float* bn_rm = (const float*)d_in[15];
  const float* bn_rv = (const float*)d_in[16];
  float* out = (float*)d_out;

  // ---- workspace layout (bytes) ----
  uint8_t* p = (uint8_t*)d_ws;
  ushort* fm_b  = (ushort*)p; p += (size_t)12288 * 2048 * 2;  // 50331648
  float*  xz    = (float*)p;  p += (size_t)12288 * 384 * 4;   // 18874368
  float*  dts   = (float*)p;  p += (size_t)12288 * 192 * 4;   // 9437184
  float*  Bsb   = (float*)p;  p += (size_t)12288 * 16 * 4;    // 786432
  float*  Csb   = (float*)p;  p += (size_t)12288 * 16 * 4;    // 786432
  ushort* ssm_b = (ushort*)p; p += (size_t)12288 * 256 * 2;   // 6291456 (K-pad 256)
  ushort* W2b   = (ushort*)p; p += (size_t)2048 * 256 * 2;    // 1048576 (K-pad 256)
  ushort* owT_b = (ushort*)p; p += (size_t)256 * 2048 * 2;    // 1048576 (padded)
  ushort* mo_wb = (ushort*)p; p += (size_t)2048 * 2048 * 2;   // 8388608
  ushort* in_wb = (ushort*)p; p += (size_t)384 * 2048 * 2;    // 1572864
  float*  scale = (float*)p;  p += 2048 * 4;
  float*  shift = (float*)p;  p += 2048 * 4;
  float*  sums  = (float*)p;  p += (size_t)64 * 192 * 2 * 4;  // 98304
  if ((size_t)(p - (uint8_t*)d_ws) > ws_size) return;

  // weights -> bf16 (+ padded transpose of out_w)
  cvt_kernel<<<4096, 256, 0, stream>>>(mo_w, mo_wb, 2048 * 2048);
  cvt_kernel<<<768, 256, 0, stream>>>(in_w, in_wb, 384 * 2048);
  hipMemsetAsync(owT_b, 0, (size_t)256 * 2048 * 2, stream);
  hipMemsetAsync(ssm_b, 0, (size_t)12288 * 256 * 2, stream);  // zero K-pad
  transpose_w<<<dim3(32, 3), 256, 0, stream>>>(out_w, owT_b);

  // LN (stats + apply/transpose -> bf16 fm)
  hipMemsetAsync(sums, 0, (size_t)64 * 192 * 2 * 4, stream);
  ln_stats<<<dim3(64, 16), 256, 0, stream>>>(feat, sums);
  ln_apply<<<dim3(64, 32, 3), 256, 0, stream>>>(feat, sums, ln_w, ln_b, fm_b);

  // GEMM1: xz = fm @ in_w^T + in_b   (M=12288, N=384, K=2048)
  mfma_gemm<0><<<dim3(3, 96), 256, 0, stream>>>(
      fm_b, in_wb, in_b, xz, nullptr);

  xproj_kernel<<<12288, 64, 0, stream>>>(xz, xpw, dtw, dts, Bsb, Csb);
  scan_kernel<<<768, 256, 0, stream>>>(xz, dts, Bsb, Csb, A_logs, Ds, ssm_b);

  // W2 = bf16(mo_w @ out_w)  (M=2048, N=192 padded to 256, K=2048), ldc=256
  mfma_gemm<2><<<dim3(2, 16), 256, 0, stream>>>(
      mo_wb, owT_b, nullptr, nullptr, W2b);
  prep_kernel<<<2048, 64, 0, stream>>>(mo_w, mo_b, out_b, bn_w, bn_b, bn_rm, bn_rv, scale, shift);

  // Final: out = relu(bn(fm@mo_w^T + ssm@W2^T)), 256x256 8-phase template
  mfma_gemm_big<<<384, 512, 0, stream>>>(fm_b, mo_wb, ssm_b, W2b, scale, shift, out);
}

// Round 5
// 597.992 us; speedup vs baseline: 1.1996x; 1.0179x over previous
//
#include <hip/hip_runtime.h>
#include <math.h>

#define EPSV 1e-5f

// Shapes (fixed): B=64, C=2048, H=24, W=8 -> L=192, M=B*L=12288
// D_in2=384, Dssm=192, N=16, R=6

typedef __attribute__((ext_vector_type(8))) __bf16 bf16x8;
typedef __attribute__((ext_vector_type(4))) float f32x4;

__device__ __forceinline__ ushort f2bf(float f) {
  union { float f; unsigned u; } v; v.f = f;
  const unsigned r = v.u + 0x7fffu + ((v.u >> 16) & 1u);  // RNE
  return (ushort)(r >> 16);
}

// async 16B/lane global->LDS: LDS dest = wave-uniform base + lane*16
#define GLOAD16(G, L) __builtin_amdgcn_global_load_lds( \
    (__attribute__((address_space(1))) void*)(G), \
    (__attribute__((address_space(3))) void*)(L), 16, 0, 0)

#define BAR() do { asm volatile("" ::: "memory"); \
  __builtin_amdgcn_s_barrier(); \
  asm volatile("" ::: "memory"); } while (0)

// DPP-based add of a permuted copy: y + perm(y). All within 16-lane DPP row.
template<int CTRL>
__device__ __forceinline__ float dpp_add(float y) {
  const int s = __builtin_amdgcn_update_dpp(0, __float_as_int(y), CTRL, 0xF, 0xF, true);
  return y + __int_as_float(s);
}
// full sum across the 16-lane row (n-group): quad xor1, xor2, then ror4, ror8
__device__ __forceinline__ float reduce16(float y) {
  y = dpp_add<0xB1>(y);    // quad_perm [1,0,3,2]
  y = dpp_add<0x4E>(y);    // quad_perm [2,3,0,1]
  y = dpp_add<0x124>(y);   // row_ror:4
  y = dpp_add<0x128>(y);   // row_ror:8
  return y;
}

// ---------------- fp32 -> bf16 convert ----------------
__global__ __launch_bounds__(256) void cvt_kernel(
    const float* __restrict__ s, ushort* __restrict__ d, int n)
{
  const int i = (blockIdx.x * 256 + threadIdx.x) * 4;
  if (i + 3 < n) {
    const float4 v = *(const float4*)(s + i);
    ushort4 o;
    o.x = f2bf(v.x); o.y = f2bf(v.y); o.z = f2bf(v.z); o.w = f2bf(v.w);
    *(ushort4*)(d + i) = o;
  }
}

// ---------------- transpose out_w (2048x192) -> bf16 out_wT (256x2048, pad 0) --
__global__ __launch_bounds__(256) void transpose_w(
    const float* __restrict__ w, ushort* __restrict__ wT)
{
  __shared__ float t[64][65];
  const int c0 = blockIdx.x * 64, d0 = blockIdx.y * 64;
  const int tl = threadIdx.x & 63, tg = threadIdx.x >> 6;
#pragma unroll
  for (int r = 0; r < 16; ++r) {
    const int c = r * 4 + tg;
    t[c][tl] = w[(size_t)(c0 + c) * 192 + d0 + tl];
  }
  __syncthreads();
#pragma unroll
  for (int r = 0; r < 16; ++r) {
    const int d = r * 4 + tg;
    wT[(size_t)(d0 + d) * 2048 + c0 + tl] = f2bf(t[tl][d]);
  }
}

// ---------------- LN stats: coalesced partial sums + atomics ----------------
__global__ __launch_bounds__(256) void ln_stats(
    const float* __restrict__ feat, float* __restrict__ sums)
{
  const int b = blockIdx.x, c0 = blockIdx.y * 128;
  const int l = threadIdx.x;
  if (l >= 192) return;
  const float* p = feat + ((size_t)b * 2048 + c0) * 192 + l;
  float s = 0.f, sq = 0.f;
  for (int c = 0; c < 128; ++c) { const float v = p[(size_t)c * 192]; s += v; sq = fmaf(v, v, sq); }
  atomicAdd(&sums[(b * 192 + l) * 2], s);
  atomicAdd(&sums[(b * 192 + l) * 2 + 1], sq);
}

// ---------------- LN apply + transpose -> bf16 fm (B*L, C) ----------------
__global__ __launch_bounds__(256) void ln_apply(
    const float* __restrict__ feat, const float* __restrict__ sums,
    const float* __restrict__ lnw, const float* __restrict__ lnb,
    ushort* __restrict__ fm)
{
  __shared__ float tile[64][65];
  __shared__ float smu[64], srs[64];
  const int b = blockIdx.x, c0 = blockIdx.y * 64, l0 = blockIdx.z * 64;
  const int tl = threadIdx.x & 63, tg = threadIdx.x >> 6;
#pragma unroll
  for (int r = 0; r < 16; ++r) {
    const int c = r * 4 + tg;
    tile[c][tl] = feat[((size_t)b * 2048 + c0 + c) * 192 + l0 + tl];
  }
  if (threadIdx.x < 64) {
    const float s  = sums[(b * 192 + l0 + threadIdx.x) * 2];
    const float sq = sums[(b * 192 + l0 + threadIdx.x) * 2 + 1];
    const float mu = s * (1.f / 2048.f);
    smu[threadIdx.x] = mu;
    srs[threadIdx.x] = rsqrtf(sq * (1.f / 2048.f) - mu * mu + EPSV);
  }
  __syncthreads();
  const float w = lnw[c0 + tl], bb = lnb[c0 + tl];
#pragma unroll
  for (int r = 0; r < 16; ++r) {
    const int ll = r * 4 + tg;
    fm[((size_t)(b * 192 + l0 + ll)) * 2048 + c0 + tl] =
        f2bf((tile[tl][ll] - smu[ll]) * srs[ll] * w + bb);
  }
}

// ---------------- MFMA K-phase: 128x128 tile, BK=32 ----------
__device__ __forceinline__ void mfma_phase(
    const ushort* __restrict__ Ag, int lda,
    const ushort* __restrict__ Bg, int ldb, int K,
    int bm, int bn, int tid, ushort* As, ushort* Bs, f32x4 acc[4][4])
{
  const int lane = tid & 63, wave = tid >> 6;
  const int wm = (wave & 1) << 6, wn = (wave >> 1) << 6;
  const int fr = lane & 15, q = lane >> 4;
  const int r0 = tid >> 2, kc = (tid & 3) << 3;   // staging row / k-chunk
  const int lb = (tid & 192) * 8;                 // wave-uniform LDS base (ushorts)
  for (int k0 = 0; k0 < K; k0 += 32) {
    __syncthreads();
    GLOAD16(Ag + (size_t)(bm + r0) * lda + k0 + kc,      As + lb);
    GLOAD16(Ag + (size_t)(bm + 64 + r0) * lda + k0 + kc, As + 2048 + lb);
    GLOAD16(Bg + (size_t)(bn + r0) * ldb + k0 + kc,      Bs + lb);
    GLOAD16(Bg + (size_t)(bn + 64 + r0) * ldb + k0 + kc, Bs + 2048 + lb);
    __syncthreads();
    bf16x8 af[4], bfr[4];
#pragma unroll
    for (int i = 0; i < 4; ++i) {
      af[i]  = *(const bf16x8*)&As[(wm + i * 16 + fr) * 32 + q * 8];
      bfr[i] = *(const bf16x8*)&Bs[(wn + i * 16 + fr) * 32 + q * 8];
    }
#pragma unroll
    for (int i = 0; i < 4; ++i)
#pragma unroll
      for (int j = 0; j < 4; ++j)
        acc[i][j] = __builtin_amdgcn_mfma_f32_16x16x32_bf16(af[i], bfr[j], acc[i][j], 0, 0, 0);
  }
}

// out = A1*B1^T + bias(p0), fp32 row-major ldc=384  (GEMM1)
__global__ __launch_bounds__(256) void mfma_gemm0(
    const ushort* __restrict__ A1, const ushort* __restrict__ B1,
    const float* __restrict__ p0, float* __restrict__ out)
{
  __shared__ ushort As[4096], Bs[4096];
  const int tid = threadIdx.x;
  const int bm = blockIdx.y * 128, bn = blockIdx.x * 128;
  f32x4 acc[4][4];
#pragma unroll
  for (int i = 0; i < 4; ++i)
#pragma unroll
    for (int j = 0; j < 4; ++j) acc[i][j] = (f32x4)(0.f);

  mfma_phase(A1, 2048, B1, 2048, 2048, bm, bn, tid, As, Bs, acc);

  const int lane = tid & 63, wave = tid >> 6;
  const int wm = (wave & 1) << 6, wn = (wave >> 1) << 6;
  const int fr = lane & 15, q = lane >> 4;
#pragma unroll
  for (int mi = 0; mi < 4; ++mi) {
    const int m0 = bm + wm + mi * 16 + q * 4;
#pragma unroll
    for (int ni = 0; ni < 4; ++ni) {
      const int n = bn + wn + ni * 16 + fr;
      const float bias = p0[n];
#pragma unroll
      for (int r = 0; r < 4; ++r)
        out[(size_t)(m0 + r) * 384 + n] = acc[mi][ni][r] + bias;
    }
  }
}

// ---- W2 split-K partials: part[z][2048][256] = mo_w[:, z*256:(z+1)*256] @ owT^T slice
// grid (2, 16, 8): bn tile 128 (N=256), bm tile 128 (M=2048), z = K-slice of 256.
__global__ __launch_bounds__(256) void w2_partial(
    const ushort* __restrict__ A1, const ushort* __restrict__ B1,
    float* __restrict__ part)
{
  __shared__ ushort As[4096], Bs[4096];
  const int tid = threadIdx.x;
  const int bm = blockIdx.y * 128, bn = blockIdx.x * 128;
  const int kz = blockIdx.z * 256;
  f32x4 acc[4][4];
#pragma unroll
  for (int i = 0; i < 4; ++i)
#pragma unroll
    for (int j = 0; j < 4; ++j) acc[i][j] = (f32x4)(0.f);

  mfma_phase(A1 + kz, 2048, B1 + kz, 2048, 256, bm, bn, tid, As, Bs, acc);

  const int lane = tid & 63, wave = tid >> 6;
  const int wm = (wave & 1) << 6, wn = (wave >> 1) << 6;
  const int fr = lane & 15, q = lane >> 4;
  float* pout = part + (size_t)blockIdx.z * 2048 * 256;
#pragma unroll
  for (int mi = 0; mi < 4; ++mi) {
    const int m0 = bm + wm + mi * 16 + q * 4;
#pragma unroll
    for (int ni = 0; ni < 4; ++ni) {
      const int n = bn + wn + ni * 16 + fr;
#pragma unroll
      for (int r = 0; r < 4; ++r)
        pout[(size_t)(m0 + r) * 256 + n] = acc[mi][ni][r];
    }
  }
}

// sum 8 partials -> bf16 W2b (ldc 256). 131072 float4s, grid 512 x 256.
__global__ __launch_bounds__(256) void w2_reduce(
    const float* __restrict__ part, ushort* __restrict__ W2b)
{
  const int i = blockIdx.x * 256 + threadIdx.x;   // float4 index
  const float4* p4 = (const float4*)part;
  float4 s = p4[i];
#pragma unroll
  for (int z = 1; z < 8; ++z) {
    const float4 v = p4[i + z * 131072];
    s.x += v.x; s.y += v.y; s.z += v.z; s.w += v.w;
  }
  ushort4 o;
  o.x = f2bf(s.x); o.y = f2bf(s.y); o.z = f2bf(s.z); o.w = f2bf(s.w);
  *(ushort4*)(W2b + (size_t)i * 4) = o;
}

// ============== Final GEMM: 256x256 tile, BK=64, 8-phase m201 template ======
// C = fm@mo_w^T (K=2048, 32 tiles) + ssm@W2^T (K=256 zero-padded, 4 tiles),
// then relu(scale*x+shift), transposed store out[(b*2048+n)*192 + l].
// Stage map during tile t (slot-safe with 2 buffers):
//   ph0: A.lo(t+1) + A.hi(t+1)  (target slot fully retired at end of t-1;
//                                issued earliest -> 3.5 phases old at the wait)
//   ph3: B.lo(t+2) + B.hi(t+2)  (B region of active slot fully read after ph2)
// Boundary invariant: only B(t+2) pair (4 loads) in flight -> vmcnt(4).
__device__ __forceinline__ void stage_half(
    int t, int kind,        // kind: 0=A.lo 1=A.hi 2=B.lo 3=B.hi
    int bm, int bn, int tid,
    const ushort* __restrict__ fmw, const ushort* __restrict__ mow,
    const ushort* __restrict__ ssmb, const ushort* __restrict__ w2b,
    ushort* As, ushort* Bs)
{
  const bool isA = (kind < 2);
  const ushort* G; int ld, k0;
  if (t < 32) { G = isA ? fmw : mow;  ld = 2048; k0 = t * 64; }
  else        { G = isA ? ssmb : w2b; ld = 256;  k0 = (t - 32) * 64; }
  const int p0 = isA ? bm : bn;
  ushort* L = (isA ? As : Bs) + (t & 1) * 16384 + (kind & 1) * 8192;
  const int w = tid >> 6, l = tid & 63;
#pragma unroll
  for (int j = 0; j < 2; ++j) {
    const int LC = j * 512 + w * 64 + l;              // 16B slot in half
    const int row = (kind & 1) * 128 + (LC >> 3);
    const int sc = (LC & 7) ^ (row & 7);
    GLOAD16(G + (size_t)(p0 + row) * ld + k0 + sc * 8, L + j * 4096 + w * 512);
  }
}

__global__ __launch_bounds__(512, 2) void mfma_gemm_big(
    const ushort* __restrict__ fmw,  const ushort* __restrict__ mow,
    const ushort* __restrict__ ssmb, const ushort* __restrict__ w2b,
    const float* __restrict__ scale, const float* __restrict__ shift,
    float* __restrict__ out)
{
  __shared__ ushort As[2 * 16384];   // [2][256][64]
  __shared__ ushort Bs[2 * 16384];
  const int tid = threadIdx.x;
  const int flat = blockIdx.x;                 // 384 blocks = 48 x 8
  const int bx = flat & 7, by = flat >> 3;     // bx = XCD id: B-panel L2-resident
  const int bm = by * 256, bn = bx * 256;

  const int lane = tid & 63, wave = tid >> 6;
  const int wr = wave >> 2, wc = wave & 3;     // 2M x 4N waves, tile 128x64
  const int fr = lane & 15, q = lane >> 4;

  constexpr int NT = 36;                       // 32 tiles K=2048 + 4 tiles K=256

  f32x4 acc[8][4];
#pragma unroll
  for (int i = 0; i < 8; ++i)
#pragma unroll
    for (int j = 0; j < 4; ++j) acc[i][j] = (f32x4)(0.f);

  // prologue: tile0 all 4 halves + B(1) pair; vmcnt(4) leaves B(1) in flight
  stage_half(0, 0, bm, bn, tid, fmw, mow, ssmb, w2b, As, Bs);
  stage_half(0, 1, bm, bn, tid, fmw, mow, ssmb, w2b, As, Bs);
  stage_half(0, 2, bm, bn, tid, fmw, mow, ssmb, w2b, As, Bs);
  stage_half(0, 3, bm, bn, tid, fmw, mow, ssmb, w2b, As, Bs);
  stage_half(1, 2, bm, bn, tid, fmw, mow, ssmb, w2b, As, Bs);
  stage_half(1, 3, bm, bn, tid, fmw, mow, ssmb, w2b, As, Bs);
  asm volatile("s_waitcnt vmcnt(4)" ::: "memory");
  BAR();

  for (int t = 0; t < NT; ++t) {
    const ushort* Ab = As + (t & 1) * 16384;
    const ushort* Bb = Bs + (t & 1) * 16384;
    bf16x8 bfr[4];
#pragma unroll
    for (int ph = 0; ph < 4; ++ph) {
      const int ks = ph >> 1, mh = ph & 1;
      const int kswz = (((ks << 2) + q) ^ (fr & 7)) << 3;
      bf16x8 af[4];
#pragma unroll
      for (int mi = 0; mi < 4; ++mi)
        af[mi] = *(const bf16x8*)&Ab[(wr * 128 + mh * 64 + mi * 16 + fr) * 64 + kswz];
      if (mh == 0) {
#pragma unroll
        for (int ni = 0; ni < 4; ++ni)
          bfr[ni] = *(const bf16x8*)&Bb[(wc * 64 + ni * 16 + fr) * 64 + kswz];
      }
      if (ph == 0) {
        if (t + 1 < NT) {
          stage_half(t + 1, 0, bm, bn, tid, fmw, mow, ssmb, w2b, As, Bs);
          stage_half(t + 1, 1, bm, bn, tid, fmw, mow, ssmb, w2b, As, Bs);
        }
      } else if (ph == 3) {
        if (t + 2 < NT) {
          stage_half(t + 2, 2, bm, bn, tid, fmw, mow, ssmb, w2b, As, Bs);
          stage_half(t + 2, 3, bm, bn, tid, fmw, mow, ssmb, w2b, As, Bs);
        }
      }
      BAR();
      __builtin_amdgcn_s_setprio(1);
#pragma unroll
      for (int mi = 0; mi < 4; ++mi)
#pragma unroll
        for (int ni = 0; ni < 4; ++ni)
          acc[mh * 4 + mi][ni] = __builtin_amdgcn_mfma_f32_16x16x32_bf16(
              af[mi], bfr[ni], acc[mh * 4 + mi][ni], 0, 0, 0);
      __builtin_amdgcn_s_setprio(0);
      if (ph == 3) {
        if (t <= 33) asm volatile("s_waitcnt vmcnt(4)" ::: "memory");
        else if (t == 34) asm volatile("s_waitcnt vmcnt(0)" ::: "memory");
      }
      BAR();
    }
  }

  // epilogue: relu(scale*x+shift), transposed float4 store
#pragma unroll
  for (int mi = 0; mi < 8; ++mi) {
    const int m0 = bm + wr * 128 + mi * 16 + q * 4;
    const int b = m0 / 192, l0 = m0 - b * 192;           // quad never straddles b
#pragma unroll
    for (int ni = 0; ni < 4; ++ni) {
      const int n = bn + wc * 64 + ni * 16 + fr;
      const float sc = scale[n], sh = shift[n];
      float4 o;
      o.x = fmaxf(fmaf(acc[mi][ni][0], sc, sh), 0.f);
      o.y = fmaxf(fmaf(acc[mi][ni][1], sc, sh), 0.f);
      o.z = fmaxf(fmaf(acc[mi][ni][2], sc, sh), 0.f);
      o.w = fmaxf(fmaf(acc[mi][ni][3], sc, sh), 0.f);
      *(float4*)(out + ((size_t)b * 2048 + n) * 192 + l0) = o;
    }
  }
}

// ---------------- x_proj + dt ----------------
__global__ __launch_bounds__(64) void xproj_kernel(
    const float* __restrict__ xz, const float* __restrict__ xpw,
    const float* __restrict__ dtw, float* __restrict__ dts,
    float* __restrict__ Bsb, float* __restrict__ Csb)
{
  const int m = blockIdx.x, tid = threadIdx.x;
  __shared__ float xrow[192];
  __shared__ float xdbl[38];
  const float* src = xz + (size_t)m * 384;
#pragma unroll
  for (int i = 0; i < 3; ++i) xrow[tid + i * 64] = src[tid + i * 64];
  __syncthreads();
  if (tid < 38) {
    float a = 0.f;
    const float* wr = xpw + tid * 192;
    for (int d = 0; d < 192; ++d) a = fmaf(xrow[d], wr[d], a);
    xdbl[tid] = a;
  }
  __syncthreads();
  if (tid < 16) Bsb[(size_t)m * 16 + tid] = xdbl[6 + tid];
  else if (tid < 32) Csb[(size_t)m * 16 + (tid - 16)] = xdbl[22 + (tid - 16)];
#pragma unroll
  for (int i = 0; i < 3; ++i) {
    const int d = tid + i * 64;
    const float* w = dtw + d * 6;
    float a = xdbl[0] * w[0] + xdbl[1] * w[1] + xdbl[2] * w[2]
            + xdbl[3] * w[3] + xdbl[4] * w[4] + xdbl[5] * w[5];
    dts[(size_t)m * 192 + d] = (a > 20.f) ? a : log1pf(__expf(a));
  }
}

// ---------------- bidirectional selective scan, transposed-LDS + DPP reduce --
__global__ __launch_bounds__(256) void scan_kernel(
    const float* __restrict__ xz, const float* __restrict__ dts,
    const float* __restrict__ Bsb, const float* __restrict__ Csb,
    const float* __restrict__ A_logs, const float* __restrict__ Ds,
    ushort* __restrict__ ssm)
{
  __shared__ float s_dt[16 * 196], s_x[16 * 196], s_B[16 * 196],
                   s_C[16 * 196], s_y[16 * 196];
  const int tid = threadIdx.x;
  const int b = blockIdx.x / 12, dblk = blockIdx.x - b * 12;
  const int d0 = dblk * 16;
  const size_t rbase = (size_t)b * 192;
  // staging: float4 global reads, transposed scalar LDS writes
  for (int i = tid; i < 768; i += 256) {
    const int l = i >> 2, j = (i & 3) << 2;
    const size_t row = rbase + l;
    const float4 dtv = *(const float4*)(dts + row * 192 + d0 + j);
    const float4 xv  = *(const float4*)(xz  + row * 384 + d0 + j);
    const float4 Bv  = *(const float4*)(Bsb + row * 16 + j);
    const float4 Cv  = *(const float4*)(Csb + row * 16 + j);
    s_dt[(j + 0) * 196 + l] = dtv.x; s_dt[(j + 1) * 196 + l] = dtv.y;
    s_dt[(j + 2) * 196 + l] = dtv.z; s_dt[(j + 3) * 196 + l] = dtv.w;
    s_x [(j + 0) * 196 + l] = xv.x;  s_x [(j + 1) * 196 + l] = xv.y;
    s_x [(j + 2) * 196 + l] = xv.z;  s_x [(j + 3) * 196 + l] = xv.w;
    s_B [(j + 0) * 196 + l] = Bv.x;  s_B [(j + 1) * 196 + l] = Bv.y;
    s_B [(j + 2) * 196 + l] = Bv.z;  s_B [(j + 3) * 196 + l] = Bv.w;
    s_C [(j + 0) * 196 + l] = Cv.x;  s_C [(j + 1) * 196 + l] = Cv.y;
    s_C [(j + 2) * 196 + l] = Cv.z;  s_C [(j + 3) * 196 + l] = Cv.w;
  }
  __syncthreads();
  const int n = tid & 15, dl = tid >> 4;
  const float Acoef = -expf(A_logs[(d0 + dl) * 16 + n]);
  const float* pdt = s_dt + dl * 196;
  const float* px  = s_x  + dl * 196;
  const float* pB  = s_B  + n * 196;
  const float* pC  = s_C  + n * 196;
  float* py = s_y + dl * 196;
  float u = 0.f;
  for (int l0 = 0; l0 < 192; l0 += 4) {
    const float4 dtv = *(const float4*)(pdt + l0);
    const float4 xv  = *(const float4*)(px + l0);
    const float4 Bv  = *(const float4*)(pB + l0);
    const float4 Cv  = *(const float4*)(pC + l0);
    u = fmaf(__expf(dtv.x * Acoef), u, dtv.x * Bv.x * xv.x);
    { float y = reduce16(u * Cv.x); if (n == 0) py[l0 + 0] = y; }
    u = fmaf(__expf(dtv.y * Acoef), u, dtv.y * Bv.y * xv.y);
    { float y = reduce16(u * Cv.y); if (n == 0) py[l0 + 1] = y; }
    u = fmaf(__expf(dtv.z * Acoef), u, dtv.z * Bv.z * xv.z);
    { float y = reduce16(u * Cv.z); if (n == 0) py[l0 + 2] = y; }
    u = fmaf(__expf(dtv.w * Acoef), u, dtv.w * Bv.w * xv.w);
    { float y = reduce16(u * Cv.w); if (n == 0) py[l0 + 3] = y; }
  }
  u = 0.f;
  for (int l0 = 188; l0 >= 0; l0 -= 4) {
    const float4 dtv = *(const float4*)(pdt + l0);
    const float4 xv  = *(const float4*)(px + l0);
    const float4 Bv  = *(const float4*)(pB + l0);
    const float4 Cv  = *(const float4*)(pC + l0);
    u = fmaf(__expf(dtv.w * Acoef), u, dtv.w * Bv.w * xv.w);
    { float y = reduce16(u * Cv.w); if (n == 0) py[l0 + 3] += y; }
    u = fmaf(__expf(dtv.z * Acoef), u, dtv.z * Bv.z * xv.z);
    { float y = reduce16(u * Cv.z); if (n == 0) py[l0 + 2] += y; }
    u = fmaf(__expf(dtv.y * Acoef), u, dtv.y * Bv.y * xv.y);
    { float y = reduce16(u * Cv.y); if (n == 0) py[l0 + 1] += y; }
    u = fmaf(__expf(dtv.x * Acoef), u, dtv.x * Bv.x * xv.x);
    { float y = reduce16(u * Cv.x); if (n == 0) py[l0 + 0] += y; }
  }
  __syncthreads();
  // epilogue: (yf+yb + 2*x*D) * silu(z) -> bf16
  for (int i = tid; i < 768; i += 256) {
    const int l = i >> 2, j = (i & 3) << 2;
    const size_t row = rbase + l;
    float4 y4, x4;
    y4.x = s_y[(j + 0) * 196 + l]; y4.y = s_y[(j + 1) * 196 + l];
    y4.z = s_y[(j + 2) * 196 + l]; y4.w = s_y[(j + 3) * 196 + l];
    x4.x = s_x[(j + 0) * 196 + l]; x4.y = s_x[(j + 1) * 196 + l];
    x4.z = s_x[(j + 2) * 196 + l]; x4.w = s_x[(j + 3) * 196 + l];
    const float4 z4 = *(const float4*)(xz + row * 384 + 192 + d0 + j);
    const float4 D4 = *(const float4*)(Ds + d0 + j);
    ushort4 o;
    o.x = f2bf((y4.x + 2.f * x4.x * D4.x) * (z4.x / (1.f + __expf(-z4.x))));
    o.y = f2bf((y4.y + 2.f * x4.y * D4.y) * (z4.y / (1.f + __expf(-z4.y))));
    o.z = f2bf((y4.z + 2.f * x4.z * D4.z) * (z4.z / (1.f + __expf(-z4.z))));
    o.w = f2bf((y4.w + 2.f * x4.w * D4.w) * (z4.w / (1.f + __expf(-z4.w))));
    *(ushort4*)(ssm + row * 256 + d0 + j) = o;
  }
}

// ---------------- BN prep ----------------
__global__ __launch_bounds__(64) void prep_kernel(
    const float* __restrict__ mo_w, const float* __restrict__ mo_b,
    const float* __restrict__ out_b,
    const float* __restrict__ bn_w, const float* __restrict__ bn_b,
    const float* __restrict__ bn_rm, const float* __restrict__ bn_rv,
    float* __restrict__ scale, float* __restrict__ shift)
{
  const int o = blockIdx.x, tid = threadIdx.x;
  float s = 0.f;
  for (int c = tid; c < 2048; c += 64) s = fmaf(mo_w[(size_t)o * 2048 + c], out_b[c], s);
#pragma unroll
  for (int off = 32; off > 0; off >>= 1) s += __shfl_down(s, off, 64);
  if (tid == 0) {
    const float b2 = s + mo_b[o];
    const float sc = bn_w[o] * rsqrtf(bn_rv[o] + EPSV);
    scale[o] = sc;
    shift[o] = (b2 - bn_rm[o]) * sc + bn_b[o];
  }
}

extern "C" void kernel_launch(void* const* d_in, const int* in_sizes, int n_in,
                              void* d_out, int out_size, void* d_ws, size_t ws_size,
                              hipStream_t stream) {
  const float* feat  = (const float*)d_in[0];
  const float* ln_w  = (const float*)d_in[1];
  const float* ln_b  = (const float*)d_in[2];
  const float* in_w  = (const float*)d_in[3];
  const float* in_b  = (const float*)d_in[4];
  const float* xpw   = (const float*)d_in[5];
  const float* dtw   = (const float*)d_in[6];
  const float* A_logs= (const float*)d_in[7];
  const float* Ds    = (const float*)d_in[8];
  const float* out_w = (const float*)d_in[9];
  const float* out_b = (const float*)d_in[10];
  const float* mo_w  = (const float*)d_in[11];
  const float* mo_b  = (const float*)d_in[12];
  const float* bn_w  = (const float*)d_in[13];
  const float* bn_b  = (const float*)d_in[14];
  const float* bn_rm = (const float*)d_in[15];
  const float* bn_rv = (const float*)d_in[16];
  float* out = (float*)d_out;

  // ---- workspace layout (bytes) ----
  uint8_t* p = (uint8_t*)d_ws;
  ushort* fm_b  = (ushort*)p; p += (size_t)12288 * 2048 * 2;  // 50331648
  float*  xz    = (float*)p;  p += (size_t)12288 * 384 * 4;   // 18874368
  float*  dts   = (float*)p;  p += (size_t)12288 * 192 * 4;   // 9437184
  float*  Bsb   = (float*)p;  p += (size_t)12288 * 16 * 4;    // 786432
  float*  Csb   = (float*)p;  p += (size_t)12288 * 16 * 4;    // 786432
  ushort* ssm_b = (ushort*)p; p += (size_t)12288 * 256 * 2;   // 6291456 (K-pad 256)
  ushort* W2b   = (ushort*)p; p += (size_t)2048 * 256 * 2;    // 1048576 (K-pad 256)
  ushort* owT_b = (ushort*)p; p += (size_t)256 * 2048 * 2;    // 1048576 (padded)
  ushort* mo_wb = (ushort*)p; p += (size_t)2048 * 2048 * 2;   // 8388608
  ushort* in_wb = (ushort*)p; p += (size_t)384 * 2048 * 2;    // 1572864
  float*  scale = (float*)p;  p += 2048 * 4;
  float*  shift = (float*)p;  p += 2048 * 4;
  float*  sums  = (float*)p;  p += (size_t)64 * 192 * 2 * 4;  // 98304
  if ((size_t)(p - (uint8_t*)d_ws) > ws_size) return;
  // W2 split-K partial buffer ALIASES xz (dead after scan_kernel):
  // 8 * 2048 * 256 * 4 = 16.78 MB <= 18.87 MB. Written only after scan.
  float* W2part = xz;

  // weights -> bf16 (+ padded transpose of out_w)
  cvt_kernel<<<4096, 256, 0, stream>>>(mo_w, mo_wb, 2048 * 2048);
  cvt_kernel<<<768, 256, 0, stream>>>(in_w, in_wb, 384 * 2048);
  hipMemsetAsync(owT_b, 0, (size_t)256 * 2048 * 2, stream);
  hipMemsetAsync(ssm_b, 0, (size_t)12288 * 256 * 2, stream);  // zero K-pad
  transpose_w<<<dim3(32, 3), 256, 0, stream>>>(out_w, owT_b);

  // LN (stats + apply/transpose -> bf16 fm)
  hipMemsetAsync(sums, 0, (size_t)64 * 192 * 2 * 4, stream);
  ln_stats<<<dim3(64, 16), 256, 0, stream>>>(feat, sums);
  ln_apply<<<dim3(64, 32, 3), 256, 0, stream>>>(feat, sums, ln_w, ln_b, fm_b);

  // GEMM1: xz = fm @ in_w^T + in_b   (M=12288, N=384, K=2048)
  mfma_gemm0<<<dim3(3, 96), 256, 0, stream>>>(fm_b, in_wb, in_b, xz);

  xproj_kernel<<<12288, 64, 0, stream>>>(xz, xpw, dtw, dts, Bsb, Csb);
  scan_kernel<<<768, 256, 0, stream>>>(xz, dts, Bsb, Csb, A_logs, Ds, ssm_b);

  // W2 = bf16(mo_w @ out_w): split-K x8 partials (into dead xz) + reduce
  w2_partial<<<dim3(2, 16, 8), 256, 0, stream>>>(mo_wb, owT_b, W2part);
  w2_reduce<<<512, 256, 0, stream>>>(W2part, W2b);
  prep_kernel<<<2048, 64, 0, stream>>>(mo_w, mo_b, out_b, bn_w, bn_b, bn_rm, bn_rv, scale, shift);

  // Final: out = relu(bn(fm@mo_w^T + ssm@W2^T)), 256x256 8-phase template
  mfma_gemm_big<<<384, 512, 0, stream>>>(fm_b, mo_wb, ssm_b, W2b, scale, shift, out);
}

// Round 6
// 585.981 us; speedup vs baseline: 1.2241x; 1.0205x over previous
//
#include <hip/hip_runtime.h>
#include <math.h>

#define EPSV 1e-5f

// Shapes (fixed): B=64, C=2048, H=24, W=8 -> L=192, M=B*L=12288
// D_in2=384, Dssm=192, N=16, R=6

typedef __attribute__((ext_vector_type(8))) __bf16 bf16x8;
typedef __attribute__((ext_vector_type(4))) float f32x4;

__device__ __forceinline__ ushort f2bf(float f) {
  union { float f; unsigned u; } v; v.f = f;
  const unsigned r = v.u + 0x7fffu + ((v.u >> 16) & 1u);  // RNE
  return (ushort)(r >> 16);
}

// async 16B/lane global->LDS: LDS dest = wave-uniform base + lane*16
#define GLOAD16(G, L) __builtin_amdgcn_global_load_lds( \
    (__attribute__((address_space(1))) void*)(G), \
    (__attribute__((address_space(3))) void*)(L), 16, 0, 0)

#define BAR() do { asm volatile("" ::: "memory"); \
  __builtin_amdgcn_s_barrier(); \
  asm volatile("" ::: "memory"); } while (0)

// DPP-based add of a permuted copy: y + perm(y). All within 16-lane DPP row.
template<int CTRL>
__device__ __forceinline__ float dpp_add(float y) {
  const int s = __builtin_amdgcn_update_dpp(0, __float_as_int(y), CTRL, 0xF, 0xF, true);
  return y + __int_as_float(s);
}
// full sum across the 16-lane row (n-group): quad xor1, xor2, then ror4, ror8
__device__ __forceinline__ float reduce16(float y) {
  y = dpp_add<0xB1>(y);    // quad_perm [1,0,3,2]
  y = dpp_add<0x4E>(y);    // quad_perm [2,3,0,1]
  y = dpp_add<0x124>(y);   // row_ror:4
  y = dpp_add<0x128>(y);   // row_ror:8
  return y;
}

// ---------------- fp32 -> bf16 convert ----------------
__global__ __launch_bounds__(256) void cvt_kernel(
    const float* __restrict__ s, ushort* __restrict__ d, int n)
{
  const int i = (blockIdx.x * 256 + threadIdx.x) * 4;
  if (i + 3 < n) {
    const float4 v = *(const float4*)(s + i);
    ushort4 o;
    o.x = f2bf(v.x); o.y = f2bf(v.y); o.z = f2bf(v.z); o.w = f2bf(v.w);
    *(ushort4*)(d + i) = o;
  }
}

// ---------------- transpose out_w (2048x192) -> bf16 out_wT (256x2048, pad 0) --
__global__ __launch_bounds__(256) void transpose_w(
    const float* __restrict__ w, ushort* __restrict__ wT)
{
  __shared__ float t[64][65];
  const int c0 = blockIdx.x * 64, d0 = blockIdx.y * 64;
  const int tl = threadIdx.x & 63, tg = threadIdx.x >> 6;
#pragma unroll
  for (int r = 0; r < 16; ++r) {
    const int c = r * 4 + tg;
    t[c][tl] = w[(size_t)(c0 + c) * 192 + d0 + tl];
  }
  __syncthreads();
#pragma unroll
  for (int r = 0; r < 16; ++r) {
    const int d = r * 4 + tg;
    wT[(size_t)(d0 + d) * 2048 + c0 + tl] = f2bf(t[tl][d]);
  }
}

// ---------------- LN stats: coalesced partial sums + atomics ----------------
__global__ __launch_bounds__(256) void ln_stats(
    const float* __restrict__ feat, float* __restrict__ sums)
{
  const int b = blockIdx.x, c0 = blockIdx.y * 128;
  const int l = threadIdx.x;
  if (l >= 192) return;
  const float* p = feat + ((size_t)b * 2048 + c0) * 192 + l;
  float s = 0.f, sq = 0.f;
  for (int c = 0; c < 128; ++c) { const float v = p[(size_t)c * 192]; s += v; sq = fmaf(v, v, sq); }
  atomicAdd(&sums[(b * 192 + l) * 2], s);
  atomicAdd(&sums[(b * 192 + l) * 2 + 1], sq);
}

// ---------------- LN apply + transpose -> bf16 fm (B*L, C) ----------------
__global__ __launch_bounds__(256) void ln_apply(
    const float* __restrict__ feat, const float* __restrict__ sums,
    const float* __restrict__ lnw, const float* __restrict__ lnb,
    ushort* __restrict__ fm)
{
  __shared__ float tile[64][65];
  __shared__ float smu[64], srs[64];
  const int b = blockIdx.x, c0 = blockIdx.y * 64, l0 = blockIdx.z * 64;
  const int tl = threadIdx.x & 63, tg = threadIdx.x >> 6;
#pragma unroll
  for (int r = 0; r < 16; ++r) {
    const int c = r * 4 + tg;
    tile[c][tl] = feat[((size_t)b * 2048 + c0 + c) * 192 + l0 + tl];
  }
  if (threadIdx.x < 64) {
    const float s  = sums[(b * 192 + l0 + threadIdx.x) * 2];
    const float sq = sums[(b * 192 + l0 + threadIdx.x) * 2 + 1];
    const float mu = s * (1.f / 2048.f);
    smu[threadIdx.x] = mu;
    srs[threadIdx.x] = rsqrtf(sq * (1.f / 2048.f) - mu * mu + EPSV);
  }
  __syncthreads();
  const float w = lnw[c0 + tl], bb = lnb[c0 + tl];
#pragma unroll
  for (int r = 0; r < 16; ++r) {
    const int ll = r * 4 + tg;
    fm[((size_t)(b * 192 + l0 + ll)) * 2048 + c0 + tl] =
        f2bf((tile[tl][ll] - smu[ll]) * srs[ll] * w + bb);
  }
}

// ---------------- MFMA K-phase: 128x128 tile, BK=32 (used by w2_partial) ----
__device__ __forceinline__ void mfma_phase(
    const ushort* __restrict__ Ag, int lda,
    const ushort* __restrict__ Bg, int ldb, int K,
    int bm, int bn, int tid, ushort* As, ushort* Bs, f32x4 acc[4][4])
{
  const int lane = tid & 63, wave = tid >> 6;
  const int wm = (wave & 1) << 6, wn = (wave >> 1) << 6;
  const int fr = lane & 15, q = lane >> 4;
  const int r0 = tid >> 2, kc = (tid & 3) << 3;   // staging row / k-chunk
  const int lb = (tid & 192) * 8;                 // wave-uniform LDS base (ushorts)
  for (int k0 = 0; k0 < K; k0 += 32) {
    __syncthreads();
    GLOAD16(Ag + (size_t)(bm + r0) * lda + k0 + kc,      As + lb);
    GLOAD16(Ag + (size_t)(bm + 64 + r0) * lda + k0 + kc, As + 2048 + lb);
    GLOAD16(Bg + (size_t)(bn + r0) * ldb + k0 + kc,      Bs + lb);
    GLOAD16(Bg + (size_t)(bn + 64 + r0) * ldb + k0 + kc, Bs + 2048 + lb);
    __syncthreads();
    bf16x8 af[4], bfr[4];
#pragma unroll
    for (int i = 0; i < 4; ++i) {
      af[i]  = *(const bf16x8*)&As[(wm + i * 16 + fr) * 32 + q * 8];
      bfr[i] = *(const bf16x8*)&Bs[(wn + i * 16 + fr) * 32 + q * 8];
    }
#pragma unroll
    for (int i = 0; i < 4; ++i)
#pragma unroll
      for (int j = 0; j < 4; ++j)
        acc[i][j] = __builtin_amdgcn_mfma_f32_16x16x32_bf16(af[i], bfr[j], acc[i][j], 0, 0, 0);
  }
}

// ---- W2 split-K partials: part[z][2048][256] = mo_w slice @ owT^T slice
__global__ __launch_bounds__(256) void w2_partial(
    const ushort* __restrict__ A1, const ushort* __restrict__ B1,
    float* __restrict__ part)
{
  __shared__ ushort As[4096], Bs[4096];
  const int tid = threadIdx.x;
  const int bm = blockIdx.y * 128, bn = blockIdx.x * 128;
  const int kz = blockIdx.z * 256;
  f32x4 acc[4][4];
#pragma unroll
  for (int i = 0; i < 4; ++i)
#pragma unroll
    for (int j = 0; j < 4; ++j) acc[i][j] = (f32x4)(0.f);

  mfma_phase(A1 + kz, 2048, B1 + kz, 2048, 256, bm, bn, tid, As, Bs, acc);

  const int lane = tid & 63, wave = tid >> 6;
  const int wm = (wave & 1) << 6, wn = (wave >> 1) << 6;
  const int fr = lane & 15, q = lane >> 4;
  float* pout = part + (size_t)blockIdx.z * 2048 * 256;
#pragma unroll
  for (int mi = 0; mi < 4; ++mi) {
    const int m0 = bm + wm + mi * 16 + q * 4;
#pragma unroll
    for (int ni = 0; ni < 4; ++ni) {
      const int n = bn + wn + ni * 16 + fr;
#pragma unroll
      for (int r = 0; r < 4; ++r)
        pout[(size_t)(m0 + r) * 256 + n] = acc[mi][ni][r];
    }
  }
}

// sum 8 partials -> bf16 W2b (ldc 256). 131072 float4s, grid 512 x 256.
__global__ __launch_bounds__(256) void w2_reduce(
    const float* __restrict__ part, ushort* __restrict__ W2b)
{
  const int i = blockIdx.x * 256 + threadIdx.x;   // float4 index
  const float4* p4 = (const float4*)part;
  float4 s = p4[i];
#pragma unroll
  for (int z = 1; z < 8; ++z) {
    const float4 v = p4[i + z * 131072];
    s.x += v.x; s.y += v.y; s.z += v.z; s.w += v.w;
  }
  ushort4 o;
  o.x = f2bf(s.x); o.y = f2bf(s.y); o.z = f2bf(s.z); o.w = f2bf(s.w);
  *(ushort4*)(W2b + (size_t)i * 4) = o;
}

// ============ GEMM1 (xz): 256x128 tile, BK=64, 4-phase pipelined ============
// xz = fm @ in_w^T + bias; M=12288, N=384, K=2048. Grid (3,48)=144 blocks
// (single round). 512 thr = 8 waves (4M x 2N), wave tile 64x64, acc[4][4].
// LDS: A[2][256][64] 64K + B[2][128][64] 32K = 96K. Same swizzle/discipline
// as mfma_gemm_big; stage map: ph0 A.lo(t+1), ph1 A.hi(t+1), ph3 B(t+2);
// boundary vmcnt(2). Race-safety: A(t+1) targets slot read in t-1 (drained by
// t-1 final barrier); B(t+2) targets current slot B, last read ph2, staged in
// ph3 section which is after ph2's closing barrier (all waves lgkm-drained).
__device__ __forceinline__ void g0_stage_A(
    int t, int kind, int bm, int tid, const ushort* __restrict__ fmw, ushort* As)
{
  ushort* L = As + (t & 1) * 16384 + kind * 8192;
  const int w = tid >> 6, l = tid & 63;
#pragma unroll
  for (int j = 0; j < 2; ++j) {
    const int LC = j * 512 + w * 64 + l;
    const int row = kind * 128 + (LC >> 3);
    const int sc = (LC & 7) ^ (row & 7);
    GLOAD16(fmw + (size_t)(bm + row) * 2048 + t * 64 + sc * 8, L + j * 4096 + w * 512);
  }
}
__device__ __forceinline__ void g0_stage_B(
    int t, int bn, int tid, const ushort* __restrict__ Bw, ushort* Bs)
{
  ushort* L = Bs + (t & 1) * 8192;
  const int w = tid >> 6, l = tid & 63;
#pragma unroll
  for (int j = 0; j < 2; ++j) {
    const int LC = j * 512 + w * 64 + l;
    const int row = LC >> 3;                 // 0..127
    const int sc = (LC & 7) ^ (row & 7);
    GLOAD16(Bw + (size_t)(bn + row) * 2048 + t * 64 + sc * 8, L + j * 4096 + w * 512);
  }
}

__global__ __launch_bounds__(512, 2) void mfma_gemm0_big(
    const ushort* __restrict__ fmw, const ushort* __restrict__ inw,
    const float* __restrict__ bias, float* __restrict__ out)
{
  __shared__ ushort As[2 * 16384];   // [2][256][64]
  __shared__ ushort Bs[2 * 8192];    // [2][128][64]
  const int tid = threadIdx.x;
  const int bm = blockIdx.y * 256, bn = blockIdx.x * 128;
  const int lane = tid & 63, wave = tid >> 6;
  const int wr = wave >> 1, wc = wave & 1;   // 4M x 2N waves, tile 64x64
  const int fr = lane & 15, q = lane >> 4;
  constexpr int NT = 32;

  f32x4 acc[4][4];
#pragma unroll
  for (int i = 0; i < 4; ++i)
#pragma unroll
    for (int j = 0; j < 4; ++j) acc[i][j] = (f32x4)(0.f);

  // prologue: tile0 (A both halves + B) + B(1); vmcnt(2) leaves B(1) in flight
  g0_stage_A(0, 0, bm, tid, fmw, As);
  g0_stage_A(0, 1, bm, tid, fmw, As);
  g0_stage_B(0, bn, tid, inw, Bs);
  g0_stage_B(1, bn, tid, inw, Bs);
  asm volatile("s_waitcnt vmcnt(2)" ::: "memory");
  BAR();

  for (int t = 0; t < NT; ++t) {
    const ushort* Ab = As + (t & 1) * 16384;
    const ushort* Bb = Bs + (t & 1) * 8192;
    bf16x8 bfr[4];
#pragma unroll
    for (int ph = 0; ph < 4; ++ph) {
      const int ks = ph >> 1, mh = ph & 1;
      const int kswz = (((ks << 2) + q) ^ (fr & 7)) << 3;
      bf16x8 af[2];
#pragma unroll
      for (int mi = 0; mi < 2; ++mi)
        af[mi] = *(const bf16x8*)&Ab[(wr * 64 + mh * 32 + mi * 16 + fr) * 64 + kswz];
      if (mh == 0) {
#pragma unroll
        for (int ni = 0; ni < 4; ++ni)
          bfr[ni] = *(const bf16x8*)&Bb[(wc * 64 + ni * 16 + fr) * 64 + kswz];
      }
      if (ph == 0) {
        if (t + 1 < NT) g0_stage_A(t + 1, 0, bm, tid, fmw, As);
      } else if (ph == 1) {
        if (t + 1 < NT) g0_stage_A(t + 1, 1, bm, tid, fmw, As);
      } else if (ph == 3) {
        if (t + 2 < NT) g0_stage_B(t + 2, bn, tid, inw, Bs);
      }
      BAR();
      __builtin_amdgcn_s_setprio(1);
#pragma unroll
      for (int mi = 0; mi < 2; ++mi)
#pragma unroll
        for (int ni = 0; ni < 4; ++ni)
          acc[mh * 2 + mi][ni] = __builtin_amdgcn_mfma_f32_16x16x32_bf16(
              af[mi], bfr[ni], acc[mh * 2 + mi][ni], 0, 0, 0);
      __builtin_amdgcn_s_setprio(0);
      if (ph == 3) {
        if (t <= NT - 3) asm volatile("s_waitcnt vmcnt(2)" ::: "memory");
        else if (t == NT - 2) asm volatile("s_waitcnt vmcnt(0)" ::: "memory");
      }
      BAR();
    }
  }

  // epilogue: + bias, fp32 store ldc=384
#pragma unroll
  for (int a = 0; a < 4; ++a) {
    const int m0 = bm + wr * 64 + a * 16 + q * 4;
#pragma unroll
    for (int ni = 0; ni < 4; ++ni) {
      const int n = bn + wc * 64 + ni * 16 + fr;
      const float bb = bias[n];
#pragma unroll
      for (int r = 0; r < 4; ++r)
        out[(size_t)(m0 + r) * 384 + n] = acc[a][ni][r] + bb;
    }
  }
}

// ============== Final GEMM: 256x256 tile, BK=64, 8-phase m201 template ======
// C = fm@mo_w^T (K=2048, 32 tiles) + ssm@W2^T (K=256 zero-padded, 4 tiles).
// Stage map (round-4 best): ph0 A.lo(t+1), ph1 A.hi(t+1), ph3 B pair(t+2);
// boundary vmcnt(4). XCD-grouped grid: each XCD owns 6 by-panels x 8 bn ->
// A-panel reused by 8 blocks on the SAME XCD's L2 (cuts A L2-miss refetch 8x).
__device__ __forceinline__ void stage_half(
    int t, int kind,        // kind: 0=A.lo 1=A.hi 2=B.lo 3=B.hi
    int bm, int bn, int tid,
    const ushort* __restrict__ fmw, const ushort* __restrict__ mow,
    const ushort* __restrict__ ssmb, const ushort* __restrict__ w2b,
    ushort* As, ushort* Bs)
{
  const bool isA = (kind < 2);
  const ushort* G; int ld, k0;
  if (t < 32) { G = isA ? fmw : mow;  ld = 2048; k0 = t * 64; }
  else        { G = isA ? ssmb : w2b; ld = 256;  k0 = (t - 32) * 64; }
  const int p0 = isA ? bm : bn;
  ushort* L = (isA ? As : Bs) + (t & 1) * 16384 + (kind & 1) * 8192;
  const int w = tid >> 6, l = tid & 63;
#pragma unroll
  for (int j = 0; j < 2; ++j) {
    const int LC = j * 512 + w * 64 + l;              // 16B slot in half
    const int row = (kind & 1) * 128 + (LC >> 3);
    const int sc = (LC & 7) ^ (row & 7);
    GLOAD16(G + (size_t)(p0 + row) * ld + k0 + sc * 8, L + j * 4096 + w * 512);
  }
}

__global__ __launch_bounds__(512, 2) void mfma_gemm_big(
    const ushort* __restrict__ fmw,  const ushort* __restrict__ mow,
    const ushort* __restrict__ ssmb, const ushort* __restrict__ w2b,
    const float* __restrict__ scale, const float* __restrict__ shift,
    float* __restrict__ out)
{
  __shared__ ushort As[2 * 16384];   // [2][256][64]
  __shared__ ushort Bs[2 * 16384];
  const int tid = threadIdx.x;
  const int flat = blockIdx.x;                 // 384 blocks
  const int xcd = flat & 7, j = flat >> 3;     // j 0..47
  const int by = xcd * 6 + (j >> 3);           // 6 A-panels per XCD
  const int bm = by * 256, bn = (j & 7) * 256; // 8 bn per XCD share the A-panel

  const int lane = tid & 63, wave = tid >> 6;
  const int wr = wave >> 2, wc = wave & 3;     // 2M x 4N waves, tile 128x64
  const int fr = lane & 15, q = lane >> 4;

  constexpr int NT = 36;                       // 32 tiles K=2048 + 4 tiles K=256

  f32x4 acc[8][4];
#pragma unroll
  for (int i = 0; i < 8; ++i)
#pragma unroll
    for (int j2 = 0; j2 < 4; ++j2) acc[i][j2] = (f32x4)(0.f);

  // prologue: tile0 all 4 halves + B(1) pair; vmcnt(4) leaves B(1) in flight
  stage_half(0, 0, bm, bn, tid, fmw, mow, ssmb, w2b, As, Bs);
  stage_half(0, 1, bm, bn, tid, fmw, mow, ssmb, w2b, As, Bs);
  stage_half(0, 2, bm, bn, tid, fmw, mow, ssmb, w2b, As, Bs);
  stage_half(0, 3, bm, bn, tid, fmw, mow, ssmb, w2b, As, Bs);
  stage_half(1, 2, bm, bn, tid, fmw, mow, ssmb, w2b, As, Bs);
  stage_half(1, 3, bm, bn, tid, fmw, mow, ssmb, w2b, As, Bs);
  asm volatile("s_waitcnt vmcnt(4)" ::: "memory");
  BAR();

  for (int t = 0; t < NT; ++t) {
    const ushort* Ab = As + (t & 1) * 16384;
    const ushort* Bb = Bs + (t & 1) * 16384;
    bf16x8 bfr[4];
#pragma unroll
    for (int ph = 0; ph < 4; ++ph) {
      const int ks = ph >> 1, mh = ph & 1;
      const int kswz = (((ks << 2) + q) ^ (fr & 7)) << 3;
      bf16x8 af[4];
#pragma unroll
      for (int mi = 0; mi < 4; ++mi)
        af[mi] = *(const bf16x8*)&Ab[(wr * 128 + mh * 64 + mi * 16 + fr) * 64 + kswz];
      if (mh == 0) {
#pragma unroll
        for (int ni = 0; ni < 4; ++ni)
          bfr[ni] = *(const bf16x8*)&Bb[(wc * 64 + ni * 16 + fr) * 64 + kswz];
      }
      if (ph == 0) {
        if (t + 1 < NT) stage_half(t + 1, 0, bm, bn, tid, fmw, mow, ssmb, w2b, As, Bs);
      } else if (ph == 1) {
        if (t + 1 < NT) stage_half(t + 1, 1, bm, bn, tid, fmw, mow, ssmb, w2b, As, Bs);
      } else if (ph == 3) {
        if (t + 2 < NT) {
          stage_half(t + 2, 2, bm, bn, tid, fmw, mow, ssmb, w2b, As, Bs);
          stage_half(t + 2, 3, bm, bn, tid, fmw, mow, ssmb, w2b, As, Bs);
        }
      }
      BAR();
      __builtin_amdgcn_s_setprio(1);
#pragma unroll
      for (int mi = 0; mi < 4; ++mi)
#pragma unroll
        for (int ni = 0; ni < 4; ++ni)
          acc[mh * 4 + mi][ni] = __builtin_amdgcn_mfma_f32_16x16x32_bf16(
              af[mi], bfr[ni], acc[mh * 4 + mi][ni], 0, 0, 0);
      __builtin_amdgcn_s_setprio(0);
      if (ph == 3) {
        if (t <= 33) asm volatile("s_waitcnt vmcnt(4)" ::: "memory");
        else if (t == 34) asm volatile("s_waitcnt vmcnt(0)" ::: "memory");
      }
      BAR();
    }
  }

  // epilogue: relu(scale*x+shift), transposed float4 store
#pragma unroll
  for (int mi = 0; mi < 8; ++mi) {
    const int m0 = bm + wr * 128 + mi * 16 + q * 4;
    const int b = m0 / 192, l0 = m0 - b * 192;           // quad never straddles b
#pragma unroll
    for (int ni = 0; ni < 4; ++ni) {
      const int n = bn + wc * 64 + ni * 16 + fr;
      const float sc = scale[n], sh = shift[n];
      float4 o;
      o.x = fmaxf(fmaf(acc[mi][ni][0], sc, sh), 0.f);
      o.y = fmaxf(fmaf(acc[mi][ni][1], sc, sh), 0.f);
      o.z = fmaxf(fmaf(acc[mi][ni][2], sc, sh), 0.f);
      o.w = fmaxf(fmaf(acc[mi][ni][3], sc, sh), 0.f);
      *(float4*)(out + ((size_t)b * 2048 + n) * 192 + l0) = o;
    }
  }
}

// ---------------- x_proj + dt ----------------
__global__ __launch_bounds__(64) void xproj_kernel(
    const float* __restrict__ xz, const float* __restrict__ xpw,
    const float* __restrict__ dtw, float* __restrict__ dts,
    float* __restrict__ Bsb, float* __restrict__ Csb)
{
  const int m = blockIdx.x, tid = threadIdx.x;
  __shared__ float xrow[192];
  __shared__ float xdbl[38];
  const float* src = xz + (size_t)m * 384;
#pragma unroll
  for (int i = 0; i < 3; ++i) xrow[tid + i * 64] = src[tid + i * 64];
  __syncthreads();
  if (tid < 38) {
    float a = 0.f;
    const float* wr = xpw + tid * 192;
    for (int d = 0; d < 192; ++d) a = fmaf(xrow[d], wr[d], a);
    xdbl[tid] = a;
  }
  __syncthreads();
  if (tid < 16) Bsb[(size_t)m * 16 + tid] = xdbl[6 + tid];
  else if (tid < 32) Csb[(size_t)m * 16 + (tid - 16)] = xdbl[22 + (tid - 16)];
#pragma unroll
  for (int i = 0; i < 3; ++i) {
    const int d = tid + i * 64;
    const float* w = dtw + d * 6;
    float a = xdbl[0] * w[0] + xdbl[1] * w[1] + xdbl[2] * w[2]
            + xdbl[3] * w[3] + xdbl[4] * w[4] + xdbl[5] * w[5];
    dts[(size_t)m * 192 + d] = (a > 20.f) ? a : log1pf(__expf(a));
  }
}

// ---------------- bidirectional selective scan, transposed-LDS + DPP reduce --
__global__ __launch_bounds__(256) void scan_kernel(
    const float* __restrict__ xz, const float* __restrict__ dts,
    const float* __restrict__ Bsb, const float* __restrict__ Csb,
    const float* __restrict__ A_logs, const float* __restrict__ Ds,
    ushort* __restrict__ ssm)
{
  __shared__ float s_dt[16 * 196], s_x[16 * 196], s_B[16 * 196],
                   s_C[16 * 196], s_y[16 * 196];
  const int tid = threadIdx.x;
  const int b = blockIdx.x / 12, dblk = blockIdx.x - b * 12;
  const int d0 = dblk * 16;
  const size_t rbase = (size_t)b * 192;
  // staging: float4 global reads, transposed scalar LDS writes
  for (int i = tid; i < 768; i += 256) {
    const int l = i >> 2, j = (i & 3) << 2;
    const size_t row = rbase + l;
    const float4 dtv = *(const float4*)(dts + row * 192 + d0 + j);
    const float4 xv  = *(const float4*)(xz  + row * 384 + d0 + j);
    const float4 Bv  = *(const float4*)(Bsb + row * 16 + j);
    const float4 Cv  = *(const float4*)(Csb + row * 16 + j);
    s_dt[(j + 0) * 196 + l] = dtv.x; s_dt[(j + 1) * 196 + l] = dtv.y;
    s_dt[(j + 2) * 196 + l] = dtv.z; s_dt[(j + 3) * 196 + l] = dtv.w;
    s_x [(j + 0) * 196 + l] = xv.x;  s_x [(j + 1) * 196 + l] = xv.y;
    s_x [(j + 2) * 196 + l] = xv.z;  s_x [(j + 3) * 196 + l] = xv.w;
    s_B [(j + 0) * 196 + l] = Bv.x;  s_B [(j + 1) * 196 + l] = Bv.y;
    s_B [(j + 2) * 196 + l] = Bv.z;  s_B [(j + 3) * 196 + l] = Bv.w;
    s_C [(j + 0) * 196 + l] = Cv.x;  s_C [(j + 1) * 196 + l] = Cv.y;
    s_C [(j + 2) * 196 + l] = Cv.z;  s_C [(j + 3) * 196 + l] = Cv.w;
  }
  __syncthreads();
  const int n = tid & 15, dl = tid >> 4;
  const float Acoef = -expf(A_logs[(d0 + dl) * 16 + n]);
  const float* pdt = s_dt + dl * 196;
  const float* px  = s_x  + dl * 196;
  const float* pB  = s_B  + n * 196;
  const float* pC  = s_C  + n * 196;
  float* py = s_y + dl * 196;
  float u = 0.f;
  for (int l0 = 0; l0 < 192; l0 += 4) {
    const float4 dtv = *(const float4*)(pdt + l0);
    const float4 xv  = *(const float4*)(px + l0);
    const float4 Bv  = *(const float4*)(pB + l0);
    const float4 Cv  = *(const float4*)(pC + l0);
    u = fmaf(__expf(dtv.x * Acoef), u, dtv.x * Bv.x * xv.x);
    { float y = reduce16(u * Cv.x); if (n == 0) py[l0 + 0] = y; }
    u = fmaf(__expf(dtv.y * Acoef), u, dtv.y * Bv.y * xv.y);
    { float y = reduce16(u * Cv.y); if (n == 0) py[l0 + 1] = y; }
    u = fmaf(__expf(dtv.z * Acoef), u, dtv.z * Bv.z * xv.z);
    { float y = reduce16(u * Cv.z); if (n == 0) py[l0 + 2] = y; }
    u = fmaf(__expf(dtv.w * Acoef), u, dtv.w * Bv.w * xv.w);
    { float y = reduce16(u * Cv.w); if (n == 0) py[l0 + 3] = y; }
  }
  u = 0.f;
  for (int l0 = 188; l0 >= 0; l0 -= 4) {
    const float4 dtv = *(const float4*)(pdt + l0);
    const float4 xv  = *(const float4*)(px + l0);
    const float4 Bv  = *(const float4*)(pB + l0);
    const float4 Cv  = *(const float4*)(pC + l0);
    u = fmaf(__expf(dtv.w * Acoef), u, dtv.w * Bv.w * xv.w);
    { float y = reduce16(u * Cv.w); if (n == 0) py[l0 + 3] += y; }
    u = fmaf(__expf(dtv.z * Acoef), u, dtv.z * Bv.z * xv.z);
    { float y = reduce16(u * Cv.z); if (n == 0) py[l0 + 2] += y; }
    u = fmaf(__expf(dtv.y * Acoef), u, dtv.y * Bv.y * xv.y);
    { float y = reduce16(u * Cv.y); if (n == 0) py[l0 + 1] += y; }
    u = fmaf(__expf(dtv.x * Acoef), u, dtv.x * Bv.x * xv.x);
    { float y = reduce16(u * Cv.x); if (n == 0) py[l0 + 0] += y; }
  }
  __syncthreads();
  // epilogue: (yf+yb + 2*x*D) * silu(z) -> bf16
  for (int i = tid; i < 768; i += 256) {
    const int l = i >> 2, j = (i & 3) << 2;
    const size_t row = rbase + l;
    float4 y4, x4;
    y4.x = s_y[(j + 0) * 196 + l]; y4.y = s_y[(j + 1) * 196 + l];
    y4.z = s_y[(j + 2) * 196 + l]; y4.w = s_y[(j + 3) * 196 + l];
    x4.x = s_x[(j + 0) * 196 + l]; x4.y = s_x[(j + 1) * 196 + l];
    x4.z = s_x[(j + 2) * 196 + l]; x4.w = s_x[(j + 3) * 196 + l];
    const float4 z4 = *(const float4*)(xz + row * 384 + 192 + d0 + j);
    const float4 D4 = *(const float4*)(Ds + d0 + j);
    ushort4 o;
    o.x = f2bf((y4.x + 2.f * x4.x * D4.x) * (z4.x / (1.f + __expf(-z4.x))));
    o.y = f2bf((y4.y + 2.f * x4.y * D4.y) * (z4.y / (1.f + __expf(-z4.y))));
    o.z = f2bf((y4.z + 2.f * x4.z * D4.z) * (z4.z / (1.f + __expf(-z4.z))));
    o.w = f2bf((y4.w + 2.f * x4.w * D4.w) * (z4.w / (1.f + __expf(-z4.w))));
    *(ushort4*)(ssm + row * 256 + d0 + j) = o;
  }
}

// ---------------- BN prep ----------------
__global__ __launch_bounds__(64) void prep_kernel(
    const float* __restrict__ mo_w, const float* __restrict__ mo_b,
    const float* __restrict__ out_b,
    const float* __restrict__ bn_w, const float* __restrict__ bn_b,
    const float* __restrict__ bn_rm, const float* __restrict__ bn_rv,
    float* __restrict__ scale, float* __restrict__ shift)
{
  const int o = blockIdx.x, tid = threadIdx.x;
  float s = 0.f;
  for (int c = tid; c < 2048; c += 64) s = fmaf(mo_w[(size_t)o * 2048 + c], out_b[c], s);
#pragma unroll
  for (int off = 32; off > 0; off >>= 1) s += __shfl_down(s, off, 64);
  if (tid == 0) {
    const float b2 = s + mo_b[o];
    const float sc = bn_w[o] * rsqrtf(bn_rv[o] + EPSV);
    scale[o] = sc;
    shift[o] = (b2 - bn_rm[o]) * sc + bn_b[o];
  }
}

extern "C" void kernel_launch(void* const* d_in, const int* in_sizes, int n_in,
                              void* d_out, int out_size, void* d_ws, size_t ws_size,
                              hipStream_t stream) {
  const float* feat  = (const float*)d_in[0];
  const float* ln_w  = (const float*)d_in[1];
  const float* ln_b  = (const float*)d_in[2];
  const float* in_w  = (const float*)d_in[3];
  const float* in_b  = (const float*)d_in[4];
  const float* xpw   = (const float*)d_in[5];
  const float* dtw   = (const float*)d_in[6];
  const float* A_logs= (const float*)d_in[7];
  const float* Ds    = (const float*)d_in[8];
  const float* out_w = (const float*)d_in[9];
  const float* out_b = (const float*)d_in[10];
  const float* mo_w  = (const float*)d_in[11];
  const float* mo_b  = (const float*)d_in[12];
  const float* bn_w  = (const float*)d_in[13];
  const float* bn_b  = (const float*)d_in[14];
  const float* bn_rm = (const float*)d_in[15];
  const float* bn_rv = (const float*)d_in[16];
  float* out = (float*)d_out;

  // ---- workspace layout (bytes) ----
  uint8_t* p = (uint8_t*)d_ws;
  ushort* fm_b  = (ushort*)p; p += (size_t)12288 * 2048 * 2;  // 50331648
  float*  xz    = (float*)p;  p += (size_t)12288 * 384 * 4;   // 18874368
  float*  dts   = (float*)p;  p += (size_t)12288 * 192 * 4;   // 9437184
  float*  Bsb   = (float*)p;  p += (size_t)12288 * 16 * 4;    // 786432
  float*  Csb   = (float*)p;  p += (size_t)12288 * 16 * 4;    // 786432
  ushort* ssm_b = (ushort*)p; p += (size_t)12288 * 256 * 2;   // 6291456 (K-pad 256)
  ushort* W2b   = (ushort*)p; p += (size_t)2048 * 256 * 2;    // 1048576 (K-pad 256)
  ushort* owT_b = (ushort*)p; p += (size_t)256 * 2048 * 2;    // 1048576 (padded)
  ushort* mo_wb = (ushort*)p; p += (size_t)2048 * 2048 * 2;   // 8388608
  ushort* in_wb = (ushort*)p; p += (size_t)384 * 2048 * 2;    // 1572864
  float*  scale = (float*)p;  p += 2048 * 4;
  float*  shift = (float*)p;  p += 2048 * 4;
  float*  sums  = (float*)p;  p += (size_t)64 * 192 * 2 * 4;  // 98304
  if ((size_t)(p - (uint8_t*)d_ws) > ws_size) return;
  // W2 split-K partial buffer ALIASES xz (dead after scan_kernel):
  // 8 * 2048 * 256 * 4 = 16.78 MB <= 18.87 MB. Written only after scan.
  float* W2part = xz;

  // weights -> bf16 (+ padded transpose of out_w)
  cvt_kernel<<<4096, 256, 0, stream>>>(mo_w, mo_wb, 2048 * 2048);
  cvt_kernel<<<768, 256, 0, stream>>>(in_w, in_wb, 384 * 2048);
  hipMemsetAsync(owT_b, 0, (size_t)256 * 2048 * 2, stream);
  hipMemsetAsync(ssm_b, 0, (size_t)12288 * 256 * 2, stream);  // zero K-pad
  transpose_w<<<dim3(32, 3), 256, 0, stream>>>(out_w, owT_b);

  // LN (stats + apply/transpose -> bf16 fm)
  hipMemsetAsync(sums, 0, (size_t)64 * 192 * 2 * 4, stream);
  ln_stats<<<dim3(64, 16), 256, 0, stream>>>(feat, sums);
  ln_apply<<<dim3(64, 32, 3), 256, 0, stream>>>(feat, sums, ln_w, ln_b, fm_b);

  // GEMM1: xz = fm @ in_w^T + in_b  (M=12288, N=384, K=2048), 4-phase pipeline
  mfma_gemm0_big<<<dim3(3, 48), 512, 0, stream>>>(fm_b, in_wb, in_b, xz);

  xproj_kernel<<<12288, 64, 0, stream>>>(xz, xpw, dtw, dts, Bsb, Csb);
  scan_kernel<<<768, 256, 0, stream>>>(xz, dts, Bsb, Csb, A_logs, Ds, ssm_b);

  // W2 = bf16(mo_w @ out_w): split-K x8 partials (into dead xz) + reduce
  w2_partial<<<dim3(2, 16, 8), 256, 0, stream>>>(mo_wb, owT_b, W2part);
  w2_reduce<<<512, 256, 0, stream>>>(W2part, W2b);
  prep_kernel<<<2048, 64, 0, stream>>>(mo_w, mo_b, out_b, bn_w, bn_b, bn_rm, bn_rv, scale, shift);

  // Final: out = relu(bn(fm@mo_w^T + ssm@W2^T)), 256x256 8-phase template
  mfma_gemm_big<<<384, 512, 0, stream>>>(fm_b, mo_wb, ssm_b, W2b, scale, shift, out);
}